// Round 1
// baseline (6995.656 us; speedup 1.0000x reference)
//
#include <hip/hip_runtime.h>
#include <hip/hip_bf16.h>
#include <math.h>

#define E_EDGES 160000
#define N_NODES 10000

// -------------------------------------------------------------------------
// prep: polynomial cutoff + build 16-dim two-body input rows
// -------------------------------------------------------------------------
__global__ __launch_bounds__(256)
void prep_kernel(const int* __restrict__ ei, const float* __restrict__ na,
                 const float* __restrict__ embed, const float* __restrict__ elen,
                 float* __restrict__ cut, float* __restrict__ A16)
{
    int e = blockIdx.x * blockDim.x + threadIdx.x;
    if (e >= E_EDGES) return;
    float r  = elen[e];
    float x  = r * (1.0f / 6.0f);
    float x2 = x * x;
    float x3 = x2 * x;
    float x6 = x3 * x3;
    // p=6: 1 - 28 x^6 + 48 x^7 - 21 x^8
    float c = 1.0f - 28.0f * x6 + 48.0f * x6 * x - 21.0f * x6 * x2;
    cut[e] = (x < 1.0f) ? c : 0.0f;
    int ctr = ei[e];
    int ngh = ei[E_EDGES + e];
    float4 ac = *(const float4*)(na + (size_t)ctr * 4);
    float4 an = *(const float4*)(na + (size_t)ngh * 4);
    float4 b0 = *(const float4*)(embed + (size_t)e * 8);
    float4 b1 = *(const float4*)(embed + (size_t)e * 8 + 4);
    float4* o = (float4*)(A16 + (size_t)e * 16);
    o[0] = ac; o[1] = an; o[2] = b0; o[3] = b1;
}

// -------------------------------------------------------------------------
// Generic fp32 tiled GEMM: C[M,N] = epilogue(A[M,K] @ B[K,N] * bscale)
// EPIL: 0=store, 1=silu, 2=*cut, 3=resnet update 1, 4=resnet update 2
// CONCAT: A row = [A1 (KA1 cols) | A2 (K-KA1 cols)]
// grid: (N/64, M/64), 256 threads
// -------------------------------------------------------------------------
template<int EPIL, bool CONCAT>
__global__ __launch_bounds__(256)
void gemm_f32(const float* __restrict__ A1, const float* __restrict__ A2,
              int KA1, int K, const float* __restrict__ B, int N,
              float bscale, float* __restrict__ C,
              const float* __restrict__ cut, const float* __restrict__ rp)
{
    __shared__ float As[16][64];
    __shared__ float Bs[16][64];
    const int tid = threadIdx.x;
    const int bn  = blockIdx.x * 64;
    const int bm  = blockIdx.y * 64;
    const int am  = tid >> 2;          // 0..63 row within tile (A load)
    const int ak  = (tid & 3) << 2;    // 0,4,8,12 k within tile (A load)
    const int bk  = tid >> 4;          // 0..15 k (B load)
    const int bn4 = (tid & 15) << 2;   // col*4 (B load)
    const int tx  = tid & 15;
    const int ty  = tid >> 4;
    const int KA2 = K - KA1;

    float acc[4][4];
    #pragma unroll
    for (int i = 0; i < 4; ++i)
        #pragma unroll
        for (int j = 0; j < 4; ++j) acc[i][j] = 0.0f;

    for (int k0 = 0; k0 < K; k0 += 16) {
        const float* Ab;
        if (!CONCAT || k0 < KA1)
            Ab = A1 + (size_t)(bm + am) * KA1 + k0 + ak;
        else
            Ab = A2 + (size_t)(bm + am) * KA2 + (k0 - KA1) + ak;
        float4 av = *(const float4*)Ab;
        As[ak + 0][am] = av.x;
        As[ak + 1][am] = av.y;
        As[ak + 2][am] = av.z;
        As[ak + 3][am] = av.w;
        float4 bv = *(const float4*)(B + (size_t)(k0 + bk) * N + bn + bn4);
        *(float4*)&Bs[bk][bn4] = bv;
        __syncthreads();
        #pragma unroll
        for (int k = 0; k < 16; ++k) {
            float4 a = *(const float4*)&As[k][ty << 2];
            float4 b = *(const float4*)&Bs[k][tx << 2];
            float a4[4] = {a.x, a.y, a.z, a.w};
            float b4[4] = {b.x, b.y, b.z, b.w};
            #pragma unroll
            for (int i = 0; i < 4; ++i)
                #pragma unroll
                for (int j = 0; j < 4; ++j)
                    acc[i][j] = fmaf(a4[i], b4[j], acc[i][j]);
        }
        __syncthreads();
    }

    float cc0 = 1.0f, cc1 = 1.0f, cc2 = 1.0f;
    if (EPIL >= 3) { cc0 = expf(rp[0]); cc1 = expf(rp[1]); cc2 = expf(rp[2]); }

    #pragma unroll
    for (int i = 0; i < 4; ++i) {
        int row = bm + (ty << 2) + i;
        float* cp = C + (size_t)row * N + bn + (tx << 2);
        float vv[4];
        #pragma unroll
        for (int j = 0; j < 4; ++j) vv[j] = acc[i][j] * bscale;
        if (EPIL == 1) {
            #pragma unroll
            for (int j = 0; j < 4; ++j) vv[j] = vv[j] / (1.0f + expf(-vv[j]));
        } else if (EPIL == 2) {
            float cu = cut[row];
            #pragma unroll
            for (int j = 0; j < 4; ++j) vv[j] *= cu;
        } else if (EPIL == 3) {
            float cu = cut[row];
            float rn = rsqrtf(cc0 * cc0 + cc1 * cc1);
            float4 old = *(const float4*)cp;
            float ov[4] = {old.x, old.y, old.z, old.w};
            #pragma unroll
            for (int j = 0; j < 4; ++j)
                vv[j] = (cc0 * ov[j] + cc1 * vv[j] * cu) * rn;
        } else if (EPIL == 4) {
            float cu = cut[row];
            float n2 = cc0 * cc0 + cc1 * cc1;
            float rn = rsqrtf(n2 + cc2 * cc2);
            float sq = sqrtf(n2);
            float4 old = *(const float4*)cp;
            float ov[4] = {old.x, old.y, old.z, old.w};
            #pragma unroll
            for (int j = 0; j < 4; ++j)
                vv[j] = (sq * ov[j] + cc2 * vv[j] * cu) * rn;
        }
        float4 outv = make_float4(vv[0], vv[1], vv[2], vv[3]);
        *(float4*)cp = outv;
    }
}

// -------------------------------------------------------------------------
// env scatter: env[center[e], u, :] += edge_attr[e,:] * wd(w_env) * env_norm
// W layout: w[e,u,k] = W[e*wstride + woff + u*2 + k]
// -------------------------------------------------------------------------
__global__ __launch_bounds__(256)
void scatter_kernel(const float* __restrict__ W, int wstride, int woff,
                    const float* __restrict__ ea, const int* __restrict__ ei,
                    float* __restrict__ env)
{
    int idx = blockIdx.x * blockDim.x + threadIdx.x;
    if (idx >= E_EDGES * 32) return;
    int e = idx >> 5, u = idx & 31;
    int c = ei[e];
    float w0 = W[(size_t)e * wstride + woff + u * 2];
    float w1 = W[(size_t)e * wstride + woff + u * 2 + 1];
    float4 a = *(const float4*)(ea + (size_t)e * 4);
    float* dst = env + (size_t)c * 128 + u * 4;
    const float en = 0.25f;  // 1/sqrt(16)
    atomicAdd(dst + 0, a.x * w0 * en);
    atomicAdd(dst + 1, a.y * w1 * en);
    atomicAdd(dst + 2, a.z * w1 * en);
    atomicAdd(dst + 3, a.w * w1 * en);
}

// -------------------------------------------------------------------------
// TP layer 0 + e3nn Linear: produces scalars [E,64] and features2 [E,32,4]
// 8 edges per block, 32 threads per edge
// -------------------------------------------------------------------------
__global__ __launch_bounds__(256)
void tp0_kernel(const float* __restrict__ W0, const float* __restrict__ ea,
                const float* __restrict__ env, const int* __restrict__ ei,
                const float* __restrict__ Ws, const float* __restrict__ Wv,
                float* __restrict__ scal, float* __restrict__ feat2)
{
    __shared__ float sc[8][64];
    __shared__ float xv[8][64][3];
    int tid = threadIdx.x;
    int le = tid >> 5;
    int u  = tid & 31;
    int e  = blockIdx.x * 8 + le;
    int c  = ei[e];
    float4 a = *(const float4*)(ea + (size_t)e * 4);
    const float* ep = env + (size_t)c * 128 + u * 4;
    float e0 = ep[0], e1 = ep[1], e2 = ep[2], e3 = ep[3];
    float wf0 = W0[(size_t)e * 128 + u * 2];
    float wf1 = W0[(size_t)e * 128 + u * 2 + 1];
    float f0 = a.x * wf0;
    float f1 = a.y * wf1, f2 = a.z * wf1, f3 = a.w * wf1;
    const float rs3 = 0.57735026918962576f;  // 1/sqrt(3)
    float t0 = f0 * e0;
    float t1 = (f1 * e1 + f2 * e2 + f3 * e3) * rs3;
    scal[(size_t)e * 64 + u]      = t0;
    scal[(size_t)e * 64 + 32 + u] = t1;
    sc[le][u]      = t0;
    sc[le][32 + u] = t1;
    xv[le][u][0] = f0 * e1; xv[le][u][1] = f0 * e2; xv[le][u][2] = f0 * e3;
    xv[le][32 + u][0] = f1 * e0; xv[le][32 + u][1] = f2 * e0; xv[le][32 + u][2] = f3 * e0;
    __syncthreads();
    // stage 2: this thread is output channel o = u of edge e
    float ys = 0.0f, yv0 = 0.0f, yv1 = 0.0f, yv2 = 0.0f;
    #pragma unroll 8
    for (int k = 0; k < 64; ++k) {
        float ws = Ws[k * 32 + u];
        float wv = Wv[k * 32 + u];
        ys  = fmaf(sc[le][k], ws, ys);
        yv0 = fmaf(xv[le][k][0], wv, yv0);
        yv1 = fmaf(xv[le][k][1], wv, yv1);
        yv2 = fmaf(xv[le][k][2], wv, yv2);
    }
    const float alpha = 0.125f;  // 1/sqrt(2U)
    float4 outv = make_float4(ys * alpha, yv0 * alpha, yv1 * alpha, yv2 * alpha);
    *(float4*)(feat2 + (size_t)e * 128 + u * 4) = outv;
}

// -------------------------------------------------------------------------
// TP layer 1 (scalar outputs only): scalars2 [E,64]
// -------------------------------------------------------------------------
__global__ __launch_bounds__(256)
void tp1_kernel(const float* __restrict__ feat2, const float* __restrict__ env,
                const int* __restrict__ ei, float* __restrict__ scal)
{
    int idx = blockIdx.x * blockDim.x + threadIdx.x;
    if (idx >= E_EDGES * 32) return;
    int e = idx >> 5, u = idx & 31;
    int c = ei[e];
    const float* ep = env + (size_t)c * 128 + u * 4;
    float4 f = *(const float4*)(feat2 + (size_t)e * 128 + u * 4);
    const float rs3 = 0.57735026918962576f;
    float t0 = f.x * ep[0];
    float t1 = (f.y * ep[1] + f.z * ep[2] + f.w * ep[3]) * rs3;
    scal[(size_t)e * 64 + u]      = t0;
    scal[(size_t)e * 64 + 32 + u] = t1;
}

// -------------------------------------------------------------------------
extern "C" void kernel_launch(void* const* d_in, const int* in_sizes, int n_in,
                              void* d_out, int out_size, void* d_ws, size_t ws_size,
                              hipStream_t stream)
{
    const int*   ei     = (const int*)d_in[0];
    const float* na     = (const float*)d_in[1];
    const float* ea     = (const float*)d_in[2];
    const float* embed  = (const float*)d_in[3];
    const float* elen   = (const float*)d_in[4];
    const float* W2b0   = (const float*)d_in[5];
    const float* W2b1   = (const float*)d_in[6];
    const float* W2b2   = (const float*)d_in[7];
    const float* Wenv0  = (const float*)d_in[8];
    const float* Wlat0  = (const float*)d_in[9];
    const float* Wlat1  = (const float*)d_in[10];
    const float* Wenv1  = (const float*)d_in[11];
    const float* Wfin0  = (const float*)d_in[12];
    const float* Wfin1  = (const float*)d_in[13];
    const float* Wlin_s = (const float*)d_in[14];
    const float* Wlin_v = (const float*)d_in[15];
    const float* rp     = (const float*)d_in[16];

    float* L = (float*)d_out;  // latents live in d_out throughout
    const size_t E = E_EDGES;

    char* ws = (char*)d_ws;
    size_t off = 0;
    auto alloc = [&](size_t b) { void* p = ws + off; off += (b + 255) & ~(size_t)255; return p; };
    float* cutb  = (float*)alloc(E * 4);
    float* A16   = (float*)alloc(E * 16 * 4);
    float* R1    = (float*)alloc(E * 128 * 4);   // H1 -> W0
    float* R2    = (float*)alloc(E * 256 * 4);   // H2 -> feat2 | WE1
    float* scal  = (float*)alloc(E * 64 * 4);    // scalars / scalars2
    float* envb  = (float*)alloc((size_t)N_NODES * 128 * 4);
    float* NLc   = (float*)alloc((size_t)32000 * 512 * 4);
    float* feat2 = R2;
    float* WE1   = R2 + E * 128;

    const float s16  = 0.25f;                   // 1/sqrt(16)
    const float s128 = 0.088388347648318447f;   // 1/sqrt(128)
    const float s256 = 0.0625f;                 // 1/sqrt(256)
    const float s512 = 0.044194173824159223f;   // 1/sqrt(512)
    const float s576 = 0.041666666666666664f;   // 1/sqrt(576)

    prep_kernel<<<(E_EDGES + 255) / 256, 256, 0, stream>>>(ei, na, embed, elen, cutb, A16);

    // ---- two-body MLP: 16 -> 128 -> 256 -> 512 (*cut)
    gemm_f32<1, false><<<dim3(2, 2500), 256, 0, stream>>>(A16, nullptr, 16, 16, W2b0, 128, s16, R1, nullptr, nullptr);
    gemm_f32<1, false><<<dim3(4, 2500), 256, 0, stream>>>(R1, nullptr, 128, 128, W2b1, 256, s128, R2, nullptr, nullptr);
    gemm_f32<2, false><<<dim3(8, 2500), 256, 0, stream>>>(R2, nullptr, 256, 256, W2b2, 512, s256, L, cutb, nullptr);

    // ---- env-embed 0: W0 = L @ Wenv0/sqrt(512)  [E,128]
    gemm_f32<0, false><<<dim3(2, 2500), 256, 0, stream>>>(L, nullptr, 512, 512, Wenv0, 128, s512, R1, nullptr, nullptr);

    // ---- env scatter 0 (w_env = W0[:,64:128])
    hipMemsetAsync(envb, 0, (size_t)N_NODES * 128 * 4, stream);
    scatter_kernel<<<E_EDGES * 32 / 256, 256, 0, stream>>>(R1, 128, 64, ea, ei, envb);

    // ---- TP0 + Linear -> scalars [E,64], feat2 [E,128]
    tp0_kernel<<<E_EDGES / 8, 256, 0, stream>>>(R1, ea, envb, ei, Wlin_s, Wlin_v, scal, feat2);

    // ---- latent resnet MLP (chunked over E): 576 -> 512 silu -> 512, update L
    for (int cidx = 0; cidx < 5; ++cidx) {
        size_t cs = (size_t)cidx * 32000;
        gemm_f32<1, true><<<dim3(8, 500), 256, 0, stream>>>(L + cs * 512, scal + cs * 64, 512, 576, Wlat0, 512, s576, NLc, nullptr, nullptr);
        gemm_f32<3, false><<<dim3(8, 500), 256, 0, stream>>>(NLc, nullptr, 512, 512, Wlat1, 512, s512, L + cs * 512, cutb + cs, rp);
    }

    // ---- env-embed 1: WE1 = L @ Wenv1/sqrt(512)  [E,64]
    gemm_f32<0, false><<<dim3(1, 2500), 256, 0, stream>>>(L, nullptr, 512, 512, Wenv1, 64, s512, WE1, nullptr, nullptr);

    // ---- env scatter 1
    hipMemsetAsync(envb, 0, (size_t)N_NODES * 128 * 4, stream);
    scatter_kernel<<<E_EDGES * 32 / 256, 256, 0, stream>>>(WE1, 64, 0, ea, ei, envb);

    // ---- TP1 -> scalars2 [E,64]
    tp1_kernel<<<E_EDGES * 32 / 256, 256, 0, stream>>>(feat2, envb, ei, scal);

    // ---- final MLP (chunked): 576 -> 512 silu -> 512, update L
    for (int cidx = 0; cidx < 5; ++cidx) {
        size_t cs = (size_t)cidx * 32000;
        gemm_f32<1, true><<<dim3(8, 500), 256, 0, stream>>>(L + cs * 512, scal + cs * 64, 512, 576, Wfin0, 512, s576, NLc, nullptr, nullptr);
        gemm_f32<4, false><<<dim3(8, 500), 256, 0, stream>>>(NLc, nullptr, 512, 512, Wfin1, 512, s512, L + cs * 512, cutb + cs, rp);
    }
}

// Round 2
// 2322.438 us; speedup vs baseline: 3.0122x; 3.0122x over previous
//
#include <hip/hip_runtime.h>
#include <math.h>

#define E_EDGES 160000
#define N_NODES 10000

typedef __attribute__((ext_vector_type(8))) __bf16 bf16x8;
typedef __attribute__((ext_vector_type(4))) float f32x4;
typedef __attribute__((ext_vector_type(4))) unsigned int u32x4;

__device__ __forceinline__ unsigned short f2bf(float x) {
    unsigned u = __float_as_uint(x);
    u += 0x7fff + ((u >> 16) & 1);   // round-to-nearest-even
    return (unsigned short)(u >> 16);
}
__device__ __forceinline__ float bf2f(unsigned short h) {
    return __uint_as_float(((unsigned)h) << 16);
}

// -------------------------------------------------------------------------
// prep: polynomial cutoff + 16-dim two-body input rows (bf16, K padded to 32)
// -------------------------------------------------------------------------
__global__ __launch_bounds__(256)
void prep_kernel(const int* __restrict__ ei, const float* __restrict__ na,
                 const float* __restrict__ embed, const float* __restrict__ elen,
                 float* __restrict__ cut, unsigned short* __restrict__ A16b)
{
    int e = blockIdx.x * blockDim.x + threadIdx.x;
    if (e >= E_EDGES) return;
    float r  = elen[e];
    float x  = r * (1.0f / 6.0f);
    float x2 = x * x;
    float x6 = x2 * x2 * x2;
    float c = 1.0f - 28.0f * x6 + 48.0f * x6 * x - 21.0f * x6 * x2;
    cut[e] = (x < 1.0f) ? c : 0.0f;
    int ctr = ei[e];
    int ngh = ei[E_EDGES + e];
    float4 ac = *(const float4*)(na + (size_t)ctr * 4);
    float4 an = *(const float4*)(na + (size_t)ngh * 4);
    float4 b0 = *(const float4*)(embed + (size_t)e * 8);
    float4 b1 = *(const float4*)(embed + (size_t)e * 8 + 4);
    unsigned short* o = A16b + (size_t)e * 32;
    o[0]  = f2bf(ac.x); o[1]  = f2bf(ac.y); o[2]  = f2bf(ac.z); o[3]  = f2bf(ac.w);
    o[4]  = f2bf(an.x); o[5]  = f2bf(an.y); o[6]  = f2bf(an.z); o[7]  = f2bf(an.w);
    o[8]  = f2bf(b0.x); o[9]  = f2bf(b0.y); o[10] = f2bf(b0.z); o[11] = f2bf(b0.w);
    o[12] = f2bf(b1.x); o[13] = f2bf(b1.y); o[14] = f2bf(b1.z); o[15] = f2bf(b1.w);
    #pragma unroll
    for (int i = 16; i < 32; ++i) o[i] = 0;
}

// -------------------------------------------------------------------------
// weight transpose + bf16 cast (+ zero pad): Bt[Npad][Kpad], Bt[n][k]=W[k][n]
// -------------------------------------------------------------------------
__global__ __launch_bounds__(256)
void wtrans_kernel(const float* __restrict__ W, int K, int N, int Kpad, int Npad,
                   unsigned short* __restrict__ Bt)
{
    int idx = blockIdx.x * blockDim.x + threadIdx.x;
    if (idx >= Npad * Kpad) return;
    int n = idx / Kpad, k = idx % Kpad;
    float v = (k < K && n < N) ? W[(size_t)k * N + n] : 0.0f;
    Bt[idx] = f2bf(v);
}

// -------------------------------------------------------------------------
// bf16 MFMA GEMM: C[M,ldc] = epilogue(A[M,K] @ Bt^T[K,N] * bscale)
// A row-major bf16 (optionally concat of A1|A2), Bt[N][K] row-major bf16.
// 128x128 tile, BK=32, 4 waves, mfma_f32_16x16x32_bf16.
// EPIL: 0=store f32, 1=silu->bf16, 2=*cut->f32+bf16,
//       3=resnet1->f32+bf16, 4=resnet2->f32
// -------------------------------------------------------------------------
template<int EPIL, bool CONCAT>
__global__ __launch_bounds__(256)
void gemm_bf16(const unsigned short* __restrict__ A1, const unsigned short* __restrict__ A2,
               int KA1, int K, const unsigned short* __restrict__ Bt,
               int ldc, int Nstore, float bscale,
               float* __restrict__ Cf, unsigned short* __restrict__ Cb,
               const float* __restrict__ cut, const float* __restrict__ rp)
{
    __shared__ __align__(16) unsigned short As[128][40];
    __shared__ __align__(16) unsigned short Bs[128][40];
    const int tid  = threadIdx.x;
    const int lane = tid & 63;
    const int wid  = tid >> 6;
    const int wr   = wid >> 1, wc = wid & 1;
    const int bn   = blockIdx.x * 128;
    const int bm   = blockIdx.y * 128;
    const int l15  = lane & 15;
    const int lk8  = (lane >> 4) << 3;     // 0,8,16,24
    const int KA2  = K - KA1;
    const int row0 = tid >> 2;             // 0..63
    const int kc   = (tid & 3) << 3;       // 0,8,16,24

    f32x4 acc[4][4] = {};

    for (int k0 = 0; k0 < K; k0 += 32) {
        const unsigned short* Ab;
        int kk, lda;
        if (!CONCAT || k0 < KA1) { Ab = A1; kk = k0 + kc; lda = KA1; }
        else                     { Ab = A2; kk = k0 - KA1 + kc; lda = KA2; }
        u32x4 a0 = *(const u32x4*)(Ab + (size_t)(bm + row0) * lda + kk);
        u32x4 a1 = *(const u32x4*)(Ab + (size_t)(bm + row0 + 64) * lda + kk);
        u32x4 b0 = *(const u32x4*)(Bt + (size_t)(bn + row0) * K + k0 + kc);
        u32x4 b1 = *(const u32x4*)(Bt + (size_t)(bn + row0 + 64) * K + k0 + kc);
        *(u32x4*)&As[row0][kc]      = a0;
        *(u32x4*)&As[row0 + 64][kc] = a1;
        *(u32x4*)&Bs[row0][kc]      = b0;
        *(u32x4*)&Bs[row0 + 64][kc] = b1;
        __syncthreads();
        bf16x8 af[4], bfr[4];
        #pragma unroll
        for (int m = 0; m < 4; ++m)
            af[m] = __builtin_bit_cast(bf16x8, *(const u32x4*)&As[wr * 64 + m * 16 + l15][lk8]);
        #pragma unroll
        for (int n = 0; n < 4; ++n)
            bfr[n] = __builtin_bit_cast(bf16x8, *(const u32x4*)&Bs[wc * 64 + n * 16 + l15][lk8]);
        #pragma unroll
        for (int m = 0; m < 4; ++m)
            #pragma unroll
            for (int n = 0; n < 4; ++n)
                acc[m][n] = __builtin_amdgcn_mfma_f32_16x16x32_bf16(af[m], bfr[n], acc[m][n], 0, 0, 0);
        __syncthreads();
    }

    float c0 = 1.0f, c1 = 1.0f, c2 = 1.0f;
    if (EPIL >= 3) { c0 = __expf(rp[0]); c1 = __expf(rp[1]); c2 = __expf(rp[2]); }

    #pragma unroll
    for (int m = 0; m < 4; ++m) {
        int rbase = bm + wr * 64 + m * 16 + ((lane >> 4) << 2);
        #pragma unroll
        for (int n = 0; n < 4; ++n) {
            int col = bn + wc * 64 + n * 16 + l15;
            if (col < Nstore) {
                #pragma unroll
                for (int r = 0; r < 4; ++r) {
                    int row = rbase + r;
                    float v = acc[m][n][r] * bscale;
                    size_t off2 = (size_t)row * ldc + col;
                    if (EPIL == 0) {
                        Cf[off2] = v;
                    } else if (EPIL == 1) {
                        v = v / (1.0f + __expf(-v));
                        Cb[off2] = f2bf(v);
                    } else if (EPIL == 2) {
                        v *= cut[row];
                        Cf[off2] = v;
                        Cb[off2] = f2bf(v);
                    } else if (EPIL == 3) {
                        float old = Cf[off2];
                        v = (c0 * old + c1 * v * cut[row]) * rsqrtf(c0 * c0 + c1 * c1);
                        Cf[off2] = v;
                        Cb[off2] = f2bf(v);
                    } else {
                        float old = Cf[off2];
                        float n2 = c0 * c0 + c1 * c1;
                        v = (sqrtf(n2) * old + c2 * v * cut[row]) * rsqrtf(n2 + c2 * c2);
                        Cf[off2] = v;
                    }
                }
            }
        }
    }
}

// -------------------------------------------------------------------------
// env scatter: env[center[e], u, :] += edge_attr[e,:] * wd(w_env) / sqrt(16)
// -------------------------------------------------------------------------
__global__ __launch_bounds__(256)
void scatter_kernel(const float* __restrict__ W, int wstride, int woff,
                    const float* __restrict__ ea, const int* __restrict__ ei,
                    float* __restrict__ env)
{
    int idx = blockIdx.x * blockDim.x + threadIdx.x;
    if (idx >= E_EDGES * 32) return;
    int e = idx >> 5, u = idx & 31;
    int c = ei[e];
    float w0 = W[(size_t)e * wstride + woff + u * 2];
    float w1 = W[(size_t)e * wstride + woff + u * 2 + 1];
    float4 a = *(const float4*)(ea + (size_t)e * 4);
    float* dst = env + (size_t)c * 128 + u * 4;
    const float en = 0.25f;  // 1/sqrt(16)
    atomicAdd(dst + 0, a.x * w0 * en);
    atomicAdd(dst + 1, a.y * w1 * en);
    atomicAdd(dst + 2, a.z * w1 * en);
    atomicAdd(dst + 3, a.w * w1 * en);
}

// -------------------------------------------------------------------------
// TP layer 0 + e3nn Linear: scalars (bf16) [E,64] and features2 (bf16) [E,32,4]
// -------------------------------------------------------------------------
__global__ __launch_bounds__(256)
void tp0_kernel(const float* __restrict__ W0, const float* __restrict__ ea,
                const float* __restrict__ env, const int* __restrict__ ei,
                const float* __restrict__ Ws, const float* __restrict__ Wv,
                unsigned short* __restrict__ scalb, unsigned short* __restrict__ feat2b)
{
    __shared__ float sc[8][64];
    __shared__ float xv[8][64][3];
    int tid = threadIdx.x;
    int le = tid >> 5;
    int u  = tid & 31;
    int e  = blockIdx.x * 8 + le;
    int c  = ei[e];
    float4 a = *(const float4*)(ea + (size_t)e * 4);
    const float* ep = env + (size_t)c * 128 + u * 4;
    float e0 = ep[0], e1 = ep[1], e2 = ep[2], e3 = ep[3];
    float wf0 = W0[(size_t)e * 128 + u * 2];
    float wf1 = W0[(size_t)e * 128 + u * 2 + 1];
    float f0 = a.x * wf0;
    float f1 = a.y * wf1, f2 = a.z * wf1, f3 = a.w * wf1;
    const float rs3 = 0.57735026918962576f;
    float t0 = f0 * e0;
    float t1 = (f1 * e1 + f2 * e2 + f3 * e3) * rs3;
    scalb[(size_t)e * 64 + u]      = f2bf(t0);
    scalb[(size_t)e * 64 + 32 + u] = f2bf(t1);
    sc[le][u]      = t0;
    sc[le][32 + u] = t1;
    xv[le][u][0] = f0 * e1; xv[le][u][1] = f0 * e2; xv[le][u][2] = f0 * e3;
    xv[le][32 + u][0] = f1 * e0; xv[le][32 + u][1] = f2 * e0; xv[le][32 + u][2] = f3 * e0;
    __syncthreads();
    float ys = 0.0f, yv0 = 0.0f, yv1 = 0.0f, yv2 = 0.0f;
    #pragma unroll 8
    for (int k = 0; k < 64; ++k) {
        float ws = Ws[k * 32 + u];
        float wv = Wv[k * 32 + u];
        ys  = fmaf(sc[le][k], ws, ys);
        yv0 = fmaf(xv[le][k][0], wv, yv0);
        yv1 = fmaf(xv[le][k][1], wv, yv1);
        yv2 = fmaf(xv[le][k][2], wv, yv2);
    }
    const float alpha = 0.125f;  // 1/sqrt(2U)
    ushort4 ov;
    ov.x = f2bf(ys * alpha);
    ov.y = f2bf(yv0 * alpha);
    ov.z = f2bf(yv1 * alpha);
    ov.w = f2bf(yv2 * alpha);
    *(ushort4*)(feat2b + (size_t)e * 128 + u * 4) = ov;
}

// -------------------------------------------------------------------------
// TP layer 1 (scalar outputs only) -> scalars2 bf16 [E,64]
// -------------------------------------------------------------------------
__global__ __launch_bounds__(256)
void tp1_kernel(const unsigned short* __restrict__ feat2b, const float* __restrict__ env,
                const int* __restrict__ ei, unsigned short* __restrict__ scalb)
{
    int idx = blockIdx.x * blockDim.x + threadIdx.x;
    if (idx >= E_EDGES * 32) return;
    int e = idx >> 5, u = idx & 31;
    int c = ei[e];
    const float* ep = env + (size_t)c * 128 + u * 4;
    ushort4 f4 = *(const ushort4*)(feat2b + (size_t)e * 128 + u * 4);
    float fx = bf2f(f4.x), fy = bf2f(f4.y), fz = bf2f(f4.z), fw = bf2f(f4.w);
    const float rs3 = 0.57735026918962576f;
    float t0 = fx * ep[0];
    float t1 = (fy * ep[1] + fz * ep[2] + fw * ep[3]) * rs3;
    scalb[(size_t)e * 64 + u]      = f2bf(t0);
    scalb[(size_t)e * 64 + 32 + u] = f2bf(t1);
}

// -------------------------------------------------------------------------
extern "C" void kernel_launch(void* const* d_in, const int* in_sizes, int n_in,
                              void* d_out, int out_size, void* d_ws, size_t ws_size,
                              hipStream_t stream)
{
    const int*   ei     = (const int*)d_in[0];
    const float* na     = (const float*)d_in[1];
    const float* ea     = (const float*)d_in[2];
    const float* embed  = (const float*)d_in[3];
    const float* elen   = (const float*)d_in[4];
    const float* W2b0   = (const float*)d_in[5];
    const float* W2b1   = (const float*)d_in[6];
    const float* W2b2   = (const float*)d_in[7];
    const float* Wenv0  = (const float*)d_in[8];
    const float* Wlat0  = (const float*)d_in[9];
    const float* Wlat1  = (const float*)d_in[10];
    const float* Wenv1  = (const float*)d_in[11];
    const float* Wfin0  = (const float*)d_in[12];
    const float* Wfin1  = (const float*)d_in[13];
    const float* Wlin_s = (const float*)d_in[14];
    const float* Wlin_v = (const float*)d_in[15];
    const float* rp     = (const float*)d_in[16];

    float* L = (float*)d_out;  // latents fp32 live in d_out
    const size_t E = E_EDGES;

    char* ws = (char*)d_ws;
    size_t off = 0;
    auto alloc = [&](size_t b) { void* p = ws + off; off += (b + 255) & ~(size_t)255; return p; };
    float*          cutb   = (float*)alloc(E * 4);
    unsigned short* wbuf   = (unsigned short*)alloc((size_t)1413120 * 2);
    float*          envb   = (float*)alloc((size_t)N_NODES * 128 * 4);
    unsigned short* scalb  = (unsigned short*)alloc(E * 64 * 2);
    unsigned short* feat2b = (unsigned short*)alloc(E * 128 * 2);
    unsigned short* Lb     = (unsigned short*)alloc(E * 512 * 2);
    char*           BIG    = (char*)alloc((size_t)124 * 1024 * 1024);

    unsigned short* A16b = (unsigned short*)BIG;                   // 10.24MB @0
    unsigned short* H1b  = (unsigned short*)(BIG + 82000000);      // 41MB   @82M
    unsigned short* H2b  = (unsigned short*)BIG;                   // 82MB   @0
    float*          R1   = (float*)BIG;                            // 82MB   @0
    unsigned short* NLb  = (unsigned short*)BIG;                   // 82MB   @0 (chunk)
    float*          WE1  = (float*)BIG;                            // 41MB   @0

    const float s16  = 0.25f;
    const float s128 = 0.088388347648318447f;
    const float s256 = 0.0625f;
    const float s512 = 0.044194173824159223f;
    const float s576 = 0.041666666666666664f;

    // weight transposes (bf16, padded)
    unsigned short* W2b0t  = wbuf;
    unsigned short* W2b1t  = wbuf + 4096;
    unsigned short* W2b2t  = wbuf + 36864;
    unsigned short* Wenv0t = wbuf + 167936;
    unsigned short* Wlat0t = wbuf + 233472;
    unsigned short* Wlat1t = wbuf + 528384;
    unsigned short* Wenv1t = wbuf + 790528;
    unsigned short* Wfin0t = wbuf + 856064;
    unsigned short* Wfin1t = wbuf + 1150976;
    auto WT = [&](const float* W, int K, int N, int Kpad, int Npad, unsigned short* dst) {
        int tot = Npad * Kpad;
        wtrans_kernel<<<(tot + 255) / 256, 256, 0, stream>>>(W, K, N, Kpad, Npad, dst);
    };
    WT(W2b0,  16, 128,  32, 128, W2b0t);
    WT(W2b1, 128, 256, 128, 256, W2b1t);
    WT(W2b2, 256, 512, 256, 512, W2b2t);
    WT(Wenv0, 512, 128, 512, 128, Wenv0t);
    WT(Wlat0, 576, 512, 576, 512, Wlat0t);
    WT(Wlat1, 512, 512, 512, 512, Wlat1t);
    WT(Wenv1, 512,  64, 512, 128, Wenv1t);
    WT(Wfin0, 576, 512, 576, 512, Wfin0t);
    WT(Wfin1, 512, 512, 512, 512, Wfin1t);

    prep_kernel<<<E_EDGES / 256, 256, 0, stream>>>(ei, na, embed, elen, cutb, A16b);

    // ---- two-body MLP: 16(->32) -> 128 -> 256 -> 512 (*cut, also bf16 copy)
    gemm_bf16<1, false><<<dim3(1, 1250), 256, 0, stream>>>(A16b, nullptr, 32, 32, W2b0t, 128, 128, s16, nullptr, H1b, nullptr, nullptr);
    gemm_bf16<1, false><<<dim3(2, 1250), 256, 0, stream>>>(H1b, nullptr, 128, 128, W2b1t, 256, 256, s128, nullptr, H2b, nullptr, nullptr);
    gemm_bf16<2, false><<<dim3(4, 1250), 256, 0, stream>>>(H2b, nullptr, 256, 256, W2b2t, 512, 512, s256, L, Lb, cutb, nullptr);

    // ---- env-embed 0: R1 = L @ Wenv0 / sqrt(512)   [E,128] f32
    gemm_bf16<0, false><<<dim3(1, 1250), 256, 0, stream>>>(Lb, nullptr, 512, 512, Wenv0t, 128, 128, s512, R1, nullptr, nullptr, nullptr);

    hipMemsetAsync(envb, 0, (size_t)N_NODES * 128 * 4, stream);
    scatter_kernel<<<E_EDGES * 32 / 256, 256, 0, stream>>>(R1, 128, 64, ea, ei, envb);
    tp0_kernel<<<E_EDGES / 8, 256, 0, stream>>>(R1, ea, envb, ei, Wlin_s, Wlin_v, scalb, feat2b);

    // ---- latent resnet MLP: [L|scal](576) -> 512 silu -> 512, resnet into L (+Lb)
    for (int c = 0; c < 2; ++c) {
        size_t cs = (size_t)c * 80000;
        gemm_bf16<1, true><<<dim3(4, 625), 256, 0, stream>>>(Lb + cs * 512, scalb + cs * 64, 512, 576, Wlat0t, 512, 512, s576, nullptr, NLb, nullptr, nullptr);
        gemm_bf16<3, false><<<dim3(4, 625), 256, 0, stream>>>(NLb, nullptr, 512, 512, Wlat1t, 512, 512, s512, L + cs * 512, Lb + cs * 512, cutb + cs, rp);
    }

    // ---- env-embed 1: WE1 = L @ Wenv1 / sqrt(512)  [E,64] f32 (N padded to 128)
    gemm_bf16<0, false><<<dim3(1, 1250), 256, 0, stream>>>(Lb, nullptr, 512, 512, Wenv1t, 64, 64, s512, WE1, nullptr, nullptr, nullptr);

    hipMemsetAsync(envb, 0, (size_t)N_NODES * 128 * 4, stream);
    scatter_kernel<<<E_EDGES * 32 / 256, 256, 0, stream>>>(WE1, 64, 0, ea, ei, envb);
    tp1_kernel<<<E_EDGES * 32 / 256, 256, 0, stream>>>(feat2b, envb, ei, scalb);

    // ---- final MLP: [L|scal2](576) -> 512 silu -> 512, resnet into L
    for (int c = 0; c < 2; ++c) {
        size_t cs = (size_t)c * 80000;
        gemm_bf16<1, true><<<dim3(4, 625), 256, 0, stream>>>(Lb + cs * 512, scalb + cs * 64, 512, 576, Wfin0t, 512, 512, s576, nullptr, NLb, nullptr, nullptr);
        gemm_bf16<4, false><<<dim3(4, 625), 256, 0, stream>>>(NLb, nullptr, 512, 512, Wfin1t, 512, 512, s512, L + cs * 512, nullptr, cutb + cs, rp);
    }
}

// Round 3
// 1435.094 us; speedup vs baseline: 4.8747x; 1.6183x over previous
//
#include <hip/hip_runtime.h>
#include <math.h>

#define E_EDGES 160000
#define N_NODES 10000

typedef __attribute__((ext_vector_type(8))) __bf16 bf16x8;
typedef __attribute__((ext_vector_type(4))) float f32x4;
typedef __attribute__((ext_vector_type(4))) unsigned int u32x4;

__device__ __forceinline__ unsigned short f2bf(float x) {
    unsigned u = __float_as_uint(x);
    u += 0x7fff + ((u >> 16) & 1);   // round-to-nearest-even
    return (unsigned short)(u >> 16);
}
__device__ __forceinline__ float bf2f(unsigned short h) {
    return __uint_as_float(((unsigned)h) << 16);
}
__device__ __forceinline__ void gload16(const unsigned short* g, unsigned short* l) {
    __builtin_amdgcn_global_load_lds(
        (const __attribute__((address_space(1))) void*)g,
        (__attribute__((address_space(3))) void*)l, 16, 0, 0);
}

// -------------------------------------------------------------------------
// prep: polynomial cutoff + 16-dim two-body input rows (bf16, K padded to 32)
// -------------------------------------------------------------------------
__global__ __launch_bounds__(256)
void prep_kernel(const int* __restrict__ ei, const float* __restrict__ na,
                 const float* __restrict__ embed, const float* __restrict__ elen,
                 float* __restrict__ cut, unsigned short* __restrict__ A16b)
{
    int e = blockIdx.x * blockDim.x + threadIdx.x;
    if (e >= E_EDGES) return;
    float r  = elen[e];
    float x  = r * (1.0f / 6.0f);
    float x2 = x * x;
    float x6 = x2 * x2 * x2;
    float c = 1.0f - 28.0f * x6 + 48.0f * x6 * x - 21.0f * x6 * x2;
    cut[e] = (x < 1.0f) ? c : 0.0f;
    int ctr = ei[e];
    int ngh = ei[E_EDGES + e];
    float4 ac = *(const float4*)(na + (size_t)ctr * 4);
    float4 an = *(const float4*)(na + (size_t)ngh * 4);
    float4 b0 = *(const float4*)(embed + (size_t)e * 8);
    float4 b1 = *(const float4*)(embed + (size_t)e * 8 + 4);
    unsigned short* o = A16b + (size_t)e * 32;
    o[0]  = f2bf(ac.x); o[1]  = f2bf(ac.y); o[2]  = f2bf(ac.z); o[3]  = f2bf(ac.w);
    o[4]  = f2bf(an.x); o[5]  = f2bf(an.y); o[6]  = f2bf(an.z); o[7]  = f2bf(an.w);
    o[8]  = f2bf(b0.x); o[9]  = f2bf(b0.y); o[10] = f2bf(b0.z); o[11] = f2bf(b0.w);
    o[12] = f2bf(b1.x); o[13] = f2bf(b1.y); o[14] = f2bf(b1.z); o[15] = f2bf(b1.w);
    #pragma unroll
    for (int i = 16; i < 32; ++i) o[i] = 0;
}

// -------------------------------------------------------------------------
// weight transpose + bf16 cast (+ zero pad): Bt[Npad][Kpad], Bt[n][k]=W[k][n]
// -------------------------------------------------------------------------
__global__ __launch_bounds__(256)
void wtrans_kernel(const float* __restrict__ W, int K, int N, int Kpad, int Npad,
                   unsigned short* __restrict__ Bt)
{
    int idx = blockIdx.x * blockDim.x + threadIdx.x;
    if (idx >= Npad * Kpad) return;
    int n = idx / Kpad, k = idx % Kpad;
    float v = (k < K && n < N) ? W[(size_t)k * N + n] : 0.0f;
    Bt[idx] = f2bf(v);
}

// -------------------------------------------------------------------------
// CSR build: histogram, scan, fill, per-segment sort (deterministic)
// -------------------------------------------------------------------------
__global__ __launch_bounds__(256)
void hist_kernel(const int* __restrict__ ei, int* __restrict__ deg)
{
    int e = blockIdx.x * blockDim.x + threadIdx.x;
    if (e >= E_EDGES) return;
    atomicAdd(&deg[ei[e]], 1);
}

__global__ __launch_bounds__(1024)
void scan_kernel(const int* __restrict__ deg, int* __restrict__ offs)
{
    __shared__ int part[1024];
    int t = threadIdx.x;
    int base = t * 10;
    int loc[10];
    int s = 0;
    #pragma unroll
    for (int i = 0; i < 10; ++i) {
        int idx = base + i;
        int d = (idx < N_NODES) ? deg[idx] : 0;
        loc[i] = s; s += d;
    }
    part[t] = s;
    __syncthreads();
    for (int o = 1; o < 1024; o <<= 1) {
        int v = (t >= o) ? part[t - o] : 0;
        __syncthreads();
        part[t] += v;
        __syncthreads();
    }
    int excl = (t > 0) ? part[t - 1] : 0;
    #pragma unroll
    for (int i = 0; i < 10; ++i) {
        int idx = base + i;
        if (idx < N_NODES) offs[idx] = excl + loc[i];
    }
    if (t == 1023) offs[N_NODES] = part[1023];
}

__global__ __launch_bounds__(256)
void fill_kernel(const int* __restrict__ ei, const int* __restrict__ offs,
                 int* __restrict__ cnt, int* __restrict__ elist)
{
    int e = blockIdx.x * blockDim.x + threadIdx.x;
    if (e >= E_EDGES) return;
    int c = ei[e];
    int pos = offs[c] + atomicAdd(&cnt[c], 1);
    elist[pos] = e;
}

__global__ __launch_bounds__(256)
void sortseg_kernel(const int* __restrict__ offs, int* __restrict__ elist)
{
    int n = blockIdx.x * blockDim.x + threadIdx.x;
    if (n >= N_NODES) return;
    int b = offs[n], en = offs[n + 1];
    for (int i = b + 1; i < en; ++i) {
        int v = elist[i];
        int j = i - 1;
        while (j >= b && elist[j] > v) { elist[j + 1] = elist[j]; --j; }
        elist[j + 1] = v;
    }
}

// -------------------------------------------------------------------------
// env gather-sum: env[n,u,comp] = sum_{e in CSR(n)} ea[e,comp]*w[e,u,sel]/sqrt(16)
// 2 nodes per block, 128 threads per node. Wb bf16.
// -------------------------------------------------------------------------
__global__ __launch_bounds__(256)
void envgather_kernel(const unsigned short* __restrict__ Wb, int wstride, int woff,
                      const float* __restrict__ ea, const int* __restrict__ offs,
                      const int* __restrict__ elist, float* __restrict__ env)
{
    int n = blockIdx.x * 2 + (threadIdx.x >> 7);
    int t = threadIdx.x & 127;
    if (n >= N_NODES) return;
    int u = t >> 2, comp = t & 3;
    int widx = woff + u * 2 + (comp ? 1 : 0);
    int beg = offs[n], end = offs[n + 1];
    float acc = 0.0f;
    for (int i = beg; i < end; ++i) {
        int e = elist[i];
        float w = bf2f(Wb[(size_t)e * wstride + widx]);
        float a = ea[(size_t)e * 4 + comp];
        acc += a * w;
    }
    env[(size_t)n * 128 + t] = acc * 0.25f;   // 1/sqrt(16)
}

// -------------------------------------------------------------------------
// bf16 MFMA GEMM, m97 structure: global_load_lds(16B) staging, linear LDS,
// 128x128 tile, BK=32, 4 waves, mfma_f32_16x16x32_bf16, XCD-bijective swizzle.
// EPIL: 0=store bf16, 1=silu->bf16, 2=*cut->bf16,
//       3=resnet1 (old=Cb)->bf16, 4=resnet2 (old=Cb)->f32 Cf
// -------------------------------------------------------------------------
template<int EPIL, bool CONCAT>
__global__ __launch_bounds__(256)
void gemm_bf16(const unsigned short* __restrict__ A1, const unsigned short* __restrict__ A2,
               int KA1, int K, const unsigned short* __restrict__ Bt,
               int nx, int ldc, int Nstore, float bscale,
               float* __restrict__ Cf, unsigned short* __restrict__ Cb,
               const float* __restrict__ cut, const float* __restrict__ rp)
{
    __shared__ __align__(16) unsigned short As[128 * 32];
    __shared__ __align__(16) unsigned short Bs[128 * 32];
    const int tid  = threadIdx.x;
    const int lane = tid & 63;
    const int wid  = tid >> 6;
    const int wr   = wid >> 1, wc = wid & 1;
    // bijective XCD swizzle (m204): contiguous row-tiles per XCD
    const int nwg = gridDim.x;
    const int fid = blockIdx.x;
    const int q = nwg >> 3, r = nwg & 7;
    const int xcd = fid & 7, j = fid >> 3;
    const int L = ((xcd < r) ? xcd * (q + 1) : r * (q + 1) + (xcd - r) * q) + j;
    const int bn = (L % nx) * 128;
    const int bm = (L / nx) * 128;

    const int l15 = lane & 15;
    const int lk8 = (lane >> 4) << 3;      // 0,8,16,24
    const int l4r = lane >> 2;             // 0..15 row-in-chunk
    const int l4k = (lane & 3) << 3;       // 0,8,16,24 shorts
    const int KA2 = K - KA1;

    f32x4 acc[4][4] = {};

    for (int k0 = 0; k0 < K; k0 += 32) {
        #pragma unroll
        for (int i = 0; i < 2; ++i) {
            int ch  = (wid << 1) + i;           // 0..7
            int row = (ch << 4) + l4r;          // 0..127
            const unsigned short* gp;
            if (!CONCAT || k0 < KA1)
                gp = A1 + (size_t)(bm + row) * KA1 + k0 + l4k;
            else
                gp = A2 + (size_t)(bm + row) * KA2 + (k0 - KA1) + l4k;
            gload16(gp, &As[ch << 9]);
            const unsigned short* gpb = Bt + (size_t)(bn + row) * K + k0 + l4k;
            gload16(gpb, &Bs[ch << 9]);
        }
        __syncthreads();
        bf16x8 af[4], bfr[4];
        #pragma unroll
        for (int m = 0; m < 4; ++m)
            af[m] = __builtin_bit_cast(bf16x8, *(const u32x4*)&As[(wr * 64 + m * 16 + l15) * 32 + lk8]);
        #pragma unroll
        for (int n = 0; n < 4; ++n)
            bfr[n] = __builtin_bit_cast(bf16x8, *(const u32x4*)&Bs[(wc * 64 + n * 16 + l15) * 32 + lk8]);
        #pragma unroll
        for (int m = 0; m < 4; ++m)
            #pragma unroll
            for (int n = 0; n < 4; ++n)
                acc[m][n] = __builtin_amdgcn_mfma_f32_16x16x32_bf16(af[m], bfr[n], acc[m][n], 0, 0, 0);
        __syncthreads();
    }

    float c0 = 1.0f, c1 = 1.0f, c2 = 1.0f;
    if (EPIL >= 3) { c0 = __expf(rp[0]); c1 = __expf(rp[1]); c2 = __expf(rp[2]); }

    #pragma unroll
    for (int m = 0; m < 4; ++m) {
        int rbase = bm + wr * 64 + m * 16 + ((lane >> 4) << 2);
        #pragma unroll
        for (int n = 0; n < 4; ++n) {
            int col = bn + wc * 64 + n * 16 + l15;
            if (col < Nstore) {
                #pragma unroll
                for (int rr = 0; rr < 4; ++rr) {
                    int row = rbase + rr;
                    float v = acc[m][n][rr] * bscale;
                    size_t off2 = (size_t)row * ldc + col;
                    if (EPIL == 0) {
                        Cb[off2] = f2bf(v);
                    } else if (EPIL == 1) {
                        v = v / (1.0f + __expf(-v));
                        Cb[off2] = f2bf(v);
                    } else if (EPIL == 2) {
                        v *= cut[row];
                        Cb[off2] = f2bf(v);
                    } else if (EPIL == 3) {
                        float old = bf2f(Cb[off2]);
                        v = (c0 * old + c1 * v * cut[row]) * rsqrtf(c0 * c0 + c1 * c1);
                        Cb[off2] = f2bf(v);
                    } else {
                        float old = bf2f(Cb[off2]);
                        float n2 = c0 * c0 + c1 * c1;
                        v = (sqrtf(n2) * old + c2 * v * cut[row]) * rsqrtf(n2 + c2 * c2);
                        Cf[off2] = v;
                    }
                }
            }
        }
    }
}

// -------------------------------------------------------------------------
// TP layer 0 + e3nn Linear (W0 bf16): scalars bf16 [E,64], features2 bf16 [E,32,4]
// -------------------------------------------------------------------------
__global__ __launch_bounds__(256)
void tp0_kernel(const unsigned short* __restrict__ W0b, const float* __restrict__ ea,
                const float* __restrict__ env, const int* __restrict__ ei,
                const float* __restrict__ Ws, const float* __restrict__ Wv,
                unsigned short* __restrict__ scalb, unsigned short* __restrict__ feat2b)
{
    __shared__ float sc[8][64];
    __shared__ float xv[8][64][3];
    int tid = threadIdx.x;
    int le = tid >> 5;
    int u  = tid & 31;
    int e  = blockIdx.x * 8 + le;
    int c  = ei[e];
    float4 a = *(const float4*)(ea + (size_t)e * 4);
    const float* ep = env + (size_t)c * 128 + u * 4;
    float e0 = ep[0], e1 = ep[1], e2 = ep[2], e3 = ep[3];
    float wf0 = bf2f(W0b[(size_t)e * 128 + u * 2]);
    float wf1 = bf2f(W0b[(size_t)e * 128 + u * 2 + 1]);
    float f0 = a.x * wf0;
    float f1 = a.y * wf1, f2 = a.z * wf1, f3 = a.w * wf1;
    const float rs3 = 0.57735026918962576f;
    float t0 = f0 * e0;
    float t1 = (f1 * e1 + f2 * e2 + f3 * e3) * rs3;
    scalb[(size_t)e * 64 + u]      = f2bf(t0);
    scalb[(size_t)e * 64 + 32 + u] = f2bf(t1);
    sc[le][u]      = t0;
    sc[le][32 + u] = t1;
    xv[le][u][0] = f0 * e1; xv[le][u][1] = f0 * e2; xv[le][u][2] = f0 * e3;
    xv[le][32 + u][0] = f1 * e0; xv[le][32 + u][1] = f2 * e0; xv[le][32 + u][2] = f3 * e0;
    __syncthreads();
    float ys = 0.0f, yv0 = 0.0f, yv1 = 0.0f, yv2 = 0.0f;
    #pragma unroll 8
    for (int k = 0; k < 64; ++k) {
        float ws = Ws[k * 32 + u];
        float wv = Wv[k * 32 + u];
        ys  = fmaf(sc[le][k], ws, ys);
        yv0 = fmaf(xv[le][k][0], wv, yv0);
        yv1 = fmaf(xv[le][k][1], wv, yv1);
        yv2 = fmaf(xv[le][k][2], wv, yv2);
    }
    const float alpha = 0.125f;  // 1/sqrt(2U)
    ushort4 ov;
    ov.x = f2bf(ys * alpha);
    ov.y = f2bf(yv0 * alpha);
    ov.z = f2bf(yv1 * alpha);
    ov.w = f2bf(yv2 * alpha);
    *(ushort4*)(feat2b + (size_t)e * 128 + u * 4) = ov;
}

// -------------------------------------------------------------------------
// TP layer 1 (scalar outputs only) -> scalars2 bf16 [E,64]
// -------------------------------------------------------------------------
__global__ __launch_bounds__(256)
void tp1_kernel(const unsigned short* __restrict__ feat2b, const float* __restrict__ env,
                const int* __restrict__ ei, unsigned short* __restrict__ scalb)
{
    int idx = blockIdx.x * blockDim.x + threadIdx.x;
    if (idx >= E_EDGES * 32) return;
    int e = idx >> 5, u = idx & 31;
    int c = ei[e];
    const float* ep = env + (size_t)c * 128 + u * 4;
    ushort4 f4 = *(const ushort4*)(feat2b + (size_t)e * 128 + u * 4);
    float fx = bf2f(f4.x), fy = bf2f(f4.y), fz = bf2f(f4.z), fw = bf2f(f4.w);
    const float rs3 = 0.57735026918962576f;
    float t0 = fx * ep[0];
    float t1 = (fy * ep[1] + fz * ep[2] + fw * ep[3]) * rs3;
    scalb[(size_t)e * 64 + u]      = f2bf(t0);
    scalb[(size_t)e * 64 + 32 + u] = f2bf(t1);
}

// -------------------------------------------------------------------------
extern "C" void kernel_launch(void* const* d_in, const int* in_sizes, int n_in,
                              void* d_out, int out_size, void* d_ws, size_t ws_size,
                              hipStream_t stream)
{
    const int*   ei     = (const int*)d_in[0];
    const float* na     = (const float*)d_in[1];
    const float* ea     = (const float*)d_in[2];
    const float* embed  = (const float*)d_in[3];
    const float* elen   = (const float*)d_in[4];
    const float* W2b0   = (const float*)d_in[5];
    const float* W2b1   = (const float*)d_in[6];
    const float* W2b2   = (const float*)d_in[7];
    const float* Wenv0  = (const float*)d_in[8];
    const float* Wlat0  = (const float*)d_in[9];
    const float* Wlat1  = (const float*)d_in[10];
    const float* Wenv1  = (const float*)d_in[11];
    const float* Wfin0  = (const float*)d_in[12];
    const float* Wfin1  = (const float*)d_in[13];
    const float* Wlin_s = (const float*)d_in[14];
    const float* Wlin_v = (const float*)d_in[15];
    const float* rp     = (const float*)d_in[16];

    float* L = (float*)d_out;   // final f32 latents (written once, EPIL4)
    const size_t E = E_EDGES;

    char* ws = (char*)d_ws;
    size_t off = 0;
    auto alloc = [&](size_t b) { void* p = ws + off; off += (b + 255) & ~(size_t)255; return p; };
    float*          cutb   = (float*)alloc(E * 4);
    unsigned short* wbuf   = (unsigned short*)alloc((size_t)1413120 * 2);
    float*          envb   = (float*)alloc((size_t)N_NODES * 128 * 4);
    unsigned short* scalb  = (unsigned short*)alloc(E * 64 * 2);
    unsigned short* feat2b = (unsigned short*)alloc(E * 128 * 2);
    unsigned short* Lb     = (unsigned short*)alloc(E * 512 * 2);
    int*            deg    = (int*)alloc(N_NODES * 4);          // also reused as cnt
    int*            offs   = (int*)alloc((N_NODES + 1) * 4);
    int*            elist  = (int*)alloc(E * 4);
    char*           BIG    = (char*)alloc((size_t)130 * 1000 * 1000);

    unsigned short* A16b = (unsigned short*)BIG;                 // [0, 10.3M)
    unsigned short* H1b  = (unsigned short*)(BIG + 82000000);    // [82M, 123M)
    unsigned short* H2b  = (unsigned short*)BIG;                 // [0, 82M)
    unsigned short* R1b  = (unsigned short*)(BIG + 82000000);    // [82M, 123M)
    unsigned short* NLb  = (unsigned short*)BIG;                 // [0, 82M) per chunk
    unsigned short* WE1b = (unsigned short*)(BIG + 82000000);    // [82M, 102.5M)

    const float s16  = 0.25f;
    const float s128 = 0.088388347648318447f;
    const float s256 = 0.0625f;
    const float s512 = 0.044194173824159223f;
    const float s576 = 0.041666666666666664f;

    // weight transposes (bf16, padded)
    unsigned short* W2b0t  = wbuf;
    unsigned short* W2b1t  = wbuf + 4096;
    unsigned short* W2b2t  = wbuf + 36864;
    unsigned short* Wenv0t = wbuf + 167936;
    unsigned short* Wlat0t = wbuf + 233472;
    unsigned short* Wlat1t = wbuf + 528384;
    unsigned short* Wenv1t = wbuf + 790528;
    unsigned short* Wfin0t = wbuf + 856064;
    unsigned short* Wfin1t = wbuf + 1150976;
    auto WT = [&](const float* W, int K, int N, int Kpad, int Npad, unsigned short* dst) {
        int tot = Npad * Kpad;
        wtrans_kernel<<<(tot + 255) / 256, 256, 0, stream>>>(W, K, N, Kpad, Npad, dst);
    };
    WT(W2b0,  16, 128,  32, 128, W2b0t);
    WT(W2b1, 128, 256, 128, 256, W2b1t);
    WT(W2b2, 256, 512, 256, 512, W2b2t);
    WT(Wenv0, 512, 128, 512, 128, Wenv0t);
    WT(Wlat0, 576, 512, 576, 512, Wlat0t);
    WT(Wlat1, 512, 512, 512, 512, Wlat1t);
    WT(Wenv1, 512,  64, 512, 128, Wenv1t);
    WT(Wfin0, 576, 512, 576, 512, Wfin0t);
    WT(Wfin1, 512, 512, 512, 512, Wfin1t);

    prep_kernel<<<E_EDGES / 256, 256, 0, stream>>>(ei, na, embed, elen, cutb, A16b);

    // ---- CSR build (deterministic: fill then per-segment sort)
    hipMemsetAsync(deg, 0, N_NODES * 4, stream);
    hist_kernel<<<E_EDGES / 256, 256, 0, stream>>>(ei, deg);
    scan_kernel<<<1, 1024, 0, stream>>>(deg, offs);
    hipMemsetAsync(deg, 0, N_NODES * 4, stream);
    fill_kernel<<<E_EDGES / 256, 256, 0, stream>>>(ei, offs, deg, elist);
    sortseg_kernel<<<(N_NODES + 255) / 256, 256, 0, stream>>>(offs, elist);

    // ---- two-body MLP: 16(->32) -> 128 -> 256 -> 512 (*cut) -> Lb
    gemm_bf16<1, false><<<1250, 256, 0, stream>>>(A16b, nullptr, 32, 32, W2b0t, 1, 128, 128, s16, nullptr, H1b, nullptr, nullptr);
    gemm_bf16<1, false><<<2500, 256, 0, stream>>>(H1b, nullptr, 128, 128, W2b1t, 2, 256, 256, s128, nullptr, H2b, nullptr, nullptr);
    gemm_bf16<2, false><<<5000, 256, 0, stream>>>(H2b, nullptr, 256, 256, W2b2t, 4, 512, 512, s256, nullptr, Lb, cutb, nullptr);

    // ---- env-embed 0: R1b = Lb @ Wenv0 / sqrt(512)  [E,128] bf16
    gemm_bf16<0, false><<<1250, 256, 0, stream>>>(Lb, nullptr, 512, 512, Wenv0t, 1, 128, 128, s512, nullptr, R1b, nullptr, nullptr);

    envgather_kernel<<<N_NODES / 2, 256, 0, stream>>>(R1b, 128, 64, ea, offs, elist, envb);
    tp0_kernel<<<E_EDGES / 8, 256, 0, stream>>>(R1b, ea, envb, ei, Wlin_s, Wlin_v, scalb, feat2b);

    // ---- latent resnet MLP: [Lb|scal](576) -> 512 silu -> 512, resnet into Lb
    for (int c = 0; c < 2; ++c) {
        size_t cs = (size_t)c * 80000;
        gemm_bf16<1, true ><<<2500, 256, 0, stream>>>(Lb + cs * 512, scalb + cs * 64, 512, 576, Wlat0t, 4, 512, 512, s576, nullptr, NLb, nullptr, nullptr);
        gemm_bf16<3, false><<<2500, 256, 0, stream>>>(NLb, nullptr, 512, 512, Wlat1t, 4, 512, 512, s512, nullptr, Lb + cs * 512, cutb + cs, rp);
    }

    // ---- env-embed 1: WE1b = Lb @ Wenv1 / sqrt(512)  [E,64] bf16 (N padded 128)
    gemm_bf16<0, false><<<1250, 256, 0, stream>>>(Lb, nullptr, 512, 512, Wenv1t, 1, 64, 64, s512, nullptr, WE1b, nullptr, nullptr);

    envgather_kernel<<<N_NODES / 2, 256, 0, stream>>>(WE1b, 64, 0, ea, offs, elist, envb);
    tp1_kernel<<<E_EDGES * 32 / 256, 256, 0, stream>>>(feat2b, envb, ei, scalb);

    // ---- final MLP: [Lb|scal2](576) -> 512 silu -> 512, resnet -> f32 d_out
    for (int c = 0; c < 2; ++c) {
        size_t cs = (size_t)c * 80000;
        gemm_bf16<1, true ><<<2500, 256, 0, stream>>>(Lb + cs * 512, scalb + cs * 64, 512, 576, Wfin0t, 4, 512, 512, s576, nullptr, NLb, nullptr, nullptr);
        gemm_bf16<4, false><<<2500, 256, 0, stream>>>(NLb, nullptr, 512, 512, Wfin1t, 4, 512, 512, s512, L + cs * 512, Lb + cs * 512, cutb + cs, rp);
    }
}

// Round 4
// 1385.611 us; speedup vs baseline: 5.0488x; 1.0357x over previous
//
#include <hip/hip_runtime.h>
#include <math.h>

#define E_EDGES 160000
#define N_NODES 10000

typedef __attribute__((ext_vector_type(8))) __bf16 bf16x8;
typedef __attribute__((ext_vector_type(4))) float f32x4;
typedef __attribute__((ext_vector_type(4))) unsigned int u32x4;

__device__ __forceinline__ unsigned short f2bf(float x) {
    unsigned u = __float_as_uint(x);
    u += 0x7fff + ((u >> 16) & 1);   // round-to-nearest-even
    return (unsigned short)(u >> 16);
}
__device__ __forceinline__ float bf2f(unsigned short h) {
    return __uint_as_float(((unsigned)h) << 16);
}
__device__ __forceinline__ void gload16(const unsigned short* g, unsigned short* l) {
    __builtin_amdgcn_global_load_lds(
        (const __attribute__((address_space(1))) void*)g,
        (__attribute__((address_space(3))) void*)l, 16, 0, 0);
}

// -------------------------------------------------------------------------
// prep (+degree histogram): cutoff + 16-dim two-body rows (bf16, K pad 32)
// -------------------------------------------------------------------------
__global__ __launch_bounds__(256)
void prep_kernel(const int* __restrict__ ei, const float* __restrict__ na,
                 const float* __restrict__ embed, const float* __restrict__ elen,
                 float* __restrict__ cut, unsigned short* __restrict__ A16b,
                 int* __restrict__ deg)
{
    int e = blockIdx.x * blockDim.x + threadIdx.x;
    if (e >= E_EDGES) return;
    float r  = elen[e];
    float x  = r * (1.0f / 6.0f);
    float x2 = x * x;
    float x6 = x2 * x2 * x2;
    float c = 1.0f - 28.0f * x6 + 48.0f * x6 * x - 21.0f * x6 * x2;
    cut[e] = (x < 1.0f) ? c : 0.0f;
    int ctr = ei[e];
    int ngh = ei[E_EDGES + e];
    atomicAdd(&deg[ctr], 1);
    float4 ac = *(const float4*)(na + (size_t)ctr * 4);
    float4 an = *(const float4*)(na + (size_t)ngh * 4);
    float4 b0 = *(const float4*)(embed + (size_t)e * 8);
    float4 b1 = *(const float4*)(embed + (size_t)e * 8 + 4);
    unsigned short* o = A16b + (size_t)e * 32;
    o[0]  = f2bf(ac.x); o[1]  = f2bf(ac.y); o[2]  = f2bf(ac.z); o[3]  = f2bf(ac.w);
    o[4]  = f2bf(an.x); o[5]  = f2bf(an.y); o[6]  = f2bf(an.z); o[7]  = f2bf(an.w);
    o[8]  = f2bf(b0.x); o[9]  = f2bf(b0.y); o[10] = f2bf(b0.z); o[11] = f2bf(b0.w);
    o[12] = f2bf(b1.x); o[13] = f2bf(b1.y); o[14] = f2bf(b1.z); o[15] = f2bf(b1.w);
    #pragma unroll
    for (int i = 16; i < 32; ++i) o[i] = 0;
}

// -------------------------------------------------------------------------
// all 9 weight transposes in one grid: coalesced reads (n fastest),
// scatter writes, scale folded in. Bt[n*Kpad+k] = W[k*N+n] * scale.
// -------------------------------------------------------------------------
__global__ __launch_bounds__(256)
void wtrans_all(const float* __restrict__ w0, const float* __restrict__ w1,
                const float* __restrict__ w2, const float* __restrict__ w3,
                const float* __restrict__ w4, const float* __restrict__ w5,
                const float* __restrict__ w6, const float* __restrict__ w7,
                const float* __restrict__ w8, unsigned short* __restrict__ wbuf)
{
    int blk = blockIdx.x;
    const float* W; int K, N, Kpad, Npad; size_t dbase; int lstart; float sc;
    const float s16  = 0.25f;
    const float s128 = 0.088388347648318447f;
    const float s256 = 0.0625f;
    const float s512 = 0.044194173824159223f;
    const float s576 = 0.041666666666666664f;
    if      (blk <   16) { W=w0; K=16;  N=128; Kpad=32;  Npad=128; dbase=0;       lstart=0;    sc=s16;  }
    else if (blk <  144) { W=w1; K=128; N=256; Kpad=128; Npad=256; dbase=4096;    lstart=16;   sc=s128; }
    else if (blk <  656) { W=w2; K=256; N=512; Kpad=256; Npad=512; dbase=36864;   lstart=144;  sc=s256; }
    else if (blk <  912) { W=w3; K=512; N=128; Kpad=512; Npad=128; dbase=167936;  lstart=656;  sc=s512; }
    else if (blk < 2064) { W=w4; K=576; N=512; Kpad=576; Npad=512; dbase=233472;  lstart=912;  sc=s576; }
    else if (blk < 3088) { W=w5; K=512; N=512; Kpad=512; Npad=512; dbase=528384;  lstart=2064; sc=s512; }
    else if (blk < 3344) { W=w6; K=512; N=64;  Kpad=512; Npad=128; dbase=790528;  lstart=3088; sc=s512; }
    else if (blk < 4496) { W=w7; K=576; N=512; Kpad=576; Npad=512; dbase=856064;  lstart=3344; sc=s576; }
    else                 { W=w8; K=512; N=512; Kpad=512; Npad=512; dbase=1150976; lstart=4496; sc=s512; }
    int local = (blk - lstart) * 256 + threadIdx.x;
    int n = local % Npad, k = local / Npad;
    if (k >= Kpad) return;
    float v = (k < K && n < N) ? W[(size_t)k * N + n] * sc : 0.0f;
    wbuf[dbase + (size_t)n * Kpad + k] = f2bf(v);
}

// -------------------------------------------------------------------------
// CSR: scan, fill, wave-bitonic per-segment sort (deterministic)
// -------------------------------------------------------------------------
__global__ __launch_bounds__(1024)
void scan_kernel(const int* __restrict__ deg, int* __restrict__ offs)
{
    __shared__ int part[1024];
    int t = threadIdx.x;
    int base = t * 10;
    int loc[10];
    int s = 0;
    #pragma unroll
    for (int i = 0; i < 10; ++i) {
        int idx = base + i;
        int d = (idx < N_NODES) ? deg[idx] : 0;
        loc[i] = s; s += d;
    }
    part[t] = s;
    __syncthreads();
    for (int o = 1; o < 1024; o <<= 1) {
        int v = (t >= o) ? part[t - o] : 0;
        __syncthreads();
        part[t] += v;
        __syncthreads();
    }
    int excl = (t > 0) ? part[t - 1] : 0;
    #pragma unroll
    for (int i = 0; i < 10; ++i) {
        int idx = base + i;
        if (idx < N_NODES) offs[idx] = excl + loc[i];
    }
    if (t == 1023) offs[N_NODES] = part[1023];
}

__global__ __launch_bounds__(256)
void fill_kernel(const int* __restrict__ ei, const int* __restrict__ offs,
                 int* __restrict__ cnt, int* __restrict__ elist)
{
    int e = blockIdx.x * blockDim.x + threadIdx.x;
    if (e >= E_EDGES) return;
    int c = ei[e];
    int pos = offs[c] + atomicAdd(&cnt[c], 1);
    elist[pos] = e;
}

__global__ __launch_bounds__(256)
void sortseg_kernel(const int* __restrict__ offs, int* __restrict__ elist)
{
    int node = blockIdx.x * 4 + (threadIdx.x >> 6);
    int l = threadIdx.x & 63;
    if (node >= N_NODES) return;
    int b = offs[node], en = offs[node + 1];
    int deg = en - b;
    if (deg <= 1) return;
    if (deg <= 64) {
        int v = (l < deg) ? elist[b + l] : 0x7fffffff;
        #pragma unroll
        for (int k = 2; k <= 64; k <<= 1) {
            #pragma unroll
            for (int j = k >> 1; j > 0; j >>= 1) {
                int o = __shfl_xor(v, j);
                bool dirUp = ((l & k) == 0);
                bool lower = ((l & j) == 0);
                int mn = v < o ? v : o;
                int mx = v < o ? o : v;
                v = (dirUp == lower) ? mn : mx;
            }
        }
        if (l < deg) elist[b + l] = v;
    } else if (l == 0) {
        for (int i = b + 1; i < en; ++i) {
            int v = elist[i];
            int j = i - 1;
            while (j >= b && elist[j] > v) { elist[j + 1] = elist[j]; --j; }
            elist[j + 1] = v;
        }
    }
}

// -------------------------------------------------------------------------
// env gather-sum (plain stores, no memset needed)
// -------------------------------------------------------------------------
__global__ __launch_bounds__(256)
void envgather_kernel(const unsigned short* __restrict__ Wb, int wstride, int woff,
                      const float* __restrict__ ea, const int* __restrict__ offs,
                      const int* __restrict__ elist, float* __restrict__ env)
{
    int n = blockIdx.x * 2 + (threadIdx.x >> 7);
    int t = threadIdx.x & 127;
    if (n >= N_NODES) return;
    int u = t >> 2, comp = t & 3;
    int widx = woff + u * 2 + (comp ? 1 : 0);
    int beg = offs[n], end = offs[n + 1];
    float acc = 0.0f;
    for (int i = beg; i < end; ++i) {
        int e = elist[i];
        float w = bf2f(Wb[(size_t)e * wstride + widx]);
        float a = ea[(size_t)e * 4 + comp];
        acc += a * w;
    }
    env[(size_t)n * 128 + t] = acc * 0.25f;   // 1/sqrt(16)
}

// -------------------------------------------------------------------------
// bf16 MFMA GEMM (m97 structure): gload_lds(16B), linear LDS [128][32],
// 128x128 tile, BK=32, 4 waves, XCD-bijective swizzle. Scales pre-folded in B.
// EPIL: 0=store bf16, 1=silu->bf16, 2=*cut->bf16, 3=resnet1(bf16), 4=resnet2->f32
// -------------------------------------------------------------------------
template<int EPIL, bool CONCAT>
__global__ __launch_bounds__(256)
void gemm_bf16(const unsigned short* __restrict__ A1, const unsigned short* __restrict__ A2,
               int KA1, int K, const unsigned short* __restrict__ Bt,
               int nx, int ldc, int Nstore,
               float* __restrict__ Cf, unsigned short* __restrict__ Cb,
               const float* __restrict__ cut, const float* __restrict__ rp)
{
    __shared__ __align__(16) unsigned short As[128 * 32];
    __shared__ __align__(16) unsigned short Bs[128 * 32];
    const int tid  = threadIdx.x;
    const int lane = tid & 63;
    const int wid  = tid >> 6;
    const int wr   = wid >> 1, wc = wid & 1;
    const int nwg = gridDim.x;
    const int fid = blockIdx.x;
    const int q = nwg >> 3, r = nwg & 7;
    const int xcd = fid & 7, j = fid >> 3;
    const int L = ((xcd < r) ? xcd * (q + 1) : r * (q + 1) + (xcd - r) * q) + j;
    const int bn = (L % nx) * 128;
    const int bm = (L / nx) * 128;

    const int l15 = lane & 15;
    const int lk8 = (lane >> 4) << 3;
    const int l4r = lane >> 2;
    const int l4k = (lane & 3) << 3;
    const int KA2 = K - KA1;

    f32x4 acc[4][4] = {};

    for (int k0 = 0; k0 < K; k0 += 32) {
        #pragma unroll
        for (int i = 0; i < 2; ++i) {
            int ch  = (wid << 1) + i;
            int row = (ch << 4) + l4r;
            const unsigned short* gp;
            if (!CONCAT || k0 < KA1)
                gp = A1 + (size_t)(bm + row) * KA1 + k0 + l4k;
            else
                gp = A2 + (size_t)(bm + row) * KA2 + (k0 - KA1) + l4k;
            gload16(gp, &As[ch << 9]);
            const unsigned short* gpb = Bt + (size_t)(bn + row) * K + k0 + l4k;
            gload16(gpb, &Bs[ch << 9]);
        }
        __syncthreads();
        bf16x8 af[4], bfr[4];
        #pragma unroll
        for (int m = 0; m < 4; ++m)
            af[m] = __builtin_bit_cast(bf16x8, *(const u32x4*)&As[(wr * 64 + m * 16 + l15) * 32 + lk8]);
        #pragma unroll
        for (int n = 0; n < 4; ++n)
            bfr[n] = __builtin_bit_cast(bf16x8, *(const u32x4*)&Bs[(wc * 64 + n * 16 + l15) * 32 + lk8]);
        #pragma unroll
        for (int m = 0; m < 4; ++m)
            #pragma unroll
            for (int n = 0; n < 4; ++n)
                acc[m][n] = __builtin_amdgcn_mfma_f32_16x16x32_bf16(af[m], bfr[n], acc[m][n], 0, 0, 0);
        __syncthreads();
    }

    float c0 = 1.0f, c1 = 1.0f, c2 = 1.0f;
    if (EPIL >= 3) { c0 = __expf(rp[0]); c1 = __expf(rp[1]); c2 = __expf(rp[2]); }

    #pragma unroll
    for (int m = 0; m < 4; ++m) {
        int rbase = bm + wr * 64 + m * 16 + ((lane >> 4) << 2);
        #pragma unroll
        for (int n = 0; n < 4; ++n) {
            int col = bn + wc * 64 + n * 16 + l15;
            if (col < Nstore) {
                #pragma unroll
                for (int rr = 0; rr < 4; ++rr) {
                    int row = rbase + rr;
                    float v = acc[m][n][rr];
                    size_t off2 = (size_t)row * ldc + col;
                    if (EPIL == 0) {
                        Cb[off2] = f2bf(v);
                    } else if (EPIL == 1) {
                        v = v / (1.0f + __expf(-v));
                        Cb[off2] = f2bf(v);
                    } else if (EPIL == 2) {
                        v *= cut[row];
                        Cb[off2] = f2bf(v);
                    } else if (EPIL == 3) {
                        float old = bf2f(Cb[off2]);
                        v = (c0 * old + c1 * v * cut[row]) * rsqrtf(c0 * c0 + c1 * c1);
                        Cb[off2] = f2bf(v);
                    } else {
                        float old = bf2f(Cb[off2]);
                        float n2 = c0 * c0 + c1 * c1;
                        v = (sqrtf(n2) * old + c2 * v * cut[row]) * rsqrtf(n2 + c2 * c2);
                        Cf[off2] = v;
                    }
                }
            }
        }
    }
}

// -------------------------------------------------------------------------
// TP0 + e3nn Linear; Ws/Wv staged in LDS with alpha folded
// -------------------------------------------------------------------------
__global__ __launch_bounds__(256)
void tp0_kernel(const unsigned short* __restrict__ W0b, const float* __restrict__ ea,
                const float* __restrict__ env, const int* __restrict__ ei,
                const float* __restrict__ Ws, const float* __restrict__ Wv,
                unsigned short* __restrict__ scalb, unsigned short* __restrict__ feat2b)
{
    __shared__ float sc[8][64];
    __shared__ float xv[8][64][3];
    __shared__ float Wsl[2048];
    __shared__ float Wvl[2048];
    int tid = threadIdx.x;
    const float alpha = 0.125f;  // 1/sqrt(2U)
    #pragma unroll
    for (int i = 0; i < 8; ++i) {
        Wsl[tid + i * 256] = Ws[tid + i * 256] * alpha;
        Wvl[tid + i * 256] = Wv[tid + i * 256] * alpha;
    }
    int le = tid >> 5;
    int u  = tid & 31;
    int e  = blockIdx.x * 8 + le;
    int c  = ei[e];
    float4 a = *(const float4*)(ea + (size_t)e * 4);
    const float* ep = env + (size_t)c * 128 + u * 4;
    float e0 = ep[0], e1 = ep[1], e2 = ep[2], e3 = ep[3];
    float wf0 = bf2f(W0b[(size_t)e * 128 + u * 2]);
    float wf1 = bf2f(W0b[(size_t)e * 128 + u * 2 + 1]);
    float f0 = a.x * wf0;
    float f1 = a.y * wf1, f2 = a.z * wf1, f3 = a.w * wf1;
    const float rs3 = 0.57735026918962576f;
    float t0 = f0 * e0;
    float t1 = (f1 * e1 + f2 * e2 + f3 * e3) * rs3;
    scalb[(size_t)e * 64 + u]      = f2bf(t0);
    scalb[(size_t)e * 64 + 32 + u] = f2bf(t1);
    sc[le][u]      = t0;
    sc[le][32 + u] = t1;
    xv[le][u][0] = f0 * e1; xv[le][u][1] = f0 * e2; xv[le][u][2] = f0 * e3;
    xv[le][32 + u][0] = f1 * e0; xv[le][32 + u][1] = f2 * e0; xv[le][32 + u][2] = f3 * e0;
    __syncthreads();
    float ys = 0.0f, yv0 = 0.0f, yv1 = 0.0f, yv2 = 0.0f;
    #pragma unroll 8
    for (int k = 0; k < 64; ++k) {
        float ws = Wsl[k * 32 + u];
        float wv = Wvl[k * 32 + u];
        ys  = fmaf(sc[le][k], ws, ys);
        yv0 = fmaf(xv[le][k][0], wv, yv0);
        yv1 = fmaf(xv[le][k][1], wv, yv1);
        yv2 = fmaf(xv[le][k][2], wv, yv2);
    }
    ushort4 ov;
    ov.x = f2bf(ys);
    ov.y = f2bf(yv0);
    ov.z = f2bf(yv1);
    ov.w = f2bf(yv2);
    *(ushort4*)(feat2b + (size_t)e * 128 + u * 4) = ov;
}

// -------------------------------------------------------------------------
// TP1 (scalar outputs only) -> scalars2 bf16 [E,64]
// -------------------------------------------------------------------------
__global__ __launch_bounds__(256)
void tp1_kernel(const unsigned short* __restrict__ feat2b, const float* __restrict__ env,
                const int* __restrict__ ei, unsigned short* __restrict__ scalb)
{
    int idx = blockIdx.x * blockDim.x + threadIdx.x;
    if (idx >= E_EDGES * 32) return;
    int e = idx >> 5, u = idx & 31;
    int c = ei[e];
    const float* ep = env + (size_t)c * 128 + u * 4;
    ushort4 f4 = *(const ushort4*)(feat2b + (size_t)e * 128 + u * 4);
    float fx = bf2f(f4.x), fy = bf2f(f4.y), fz = bf2f(f4.z), fw = bf2f(f4.w);
    const float rs3 = 0.57735026918962576f;
    float t0 = fx * ep[0];
    float t1 = (fy * ep[1] + fz * ep[2] + fw * ep[3]) * rs3;
    scalb[(size_t)e * 64 + u]      = f2bf(t0);
    scalb[(size_t)e * 64 + 32 + u] = f2bf(t1);
}

// -------------------------------------------------------------------------
extern "C" void kernel_launch(void* const* d_in, const int* in_sizes, int n_in,
                              void* d_out, int out_size, void* d_ws, size_t ws_size,
                              hipStream_t stream)
{
    const int*   ei     = (const int*)d_in[0];
    const float* na     = (const float*)d_in[1];
    const float* ea     = (const float*)d_in[2];
    const float* embed  = (const float*)d_in[3];
    const float* elen   = (const float*)d_in[4];
    const float* W2b0   = (const float*)d_in[5];
    const float* W2b1   = (const float*)d_in[6];
    const float* W2b2   = (const float*)d_in[7];
    const float* Wenv0  = (const float*)d_in[8];
    const float* Wlat0  = (const float*)d_in[9];
    const float* Wlat1  = (const float*)d_in[10];
    const float* Wenv1  = (const float*)d_in[11];
    const float* Wfin0  = (const float*)d_in[12];
    const float* Wfin1  = (const float*)d_in[13];
    const float* Wlin_s = (const float*)d_in[14];
    const float* Wlin_v = (const float*)d_in[15];
    const float* rp     = (const float*)d_in[16];

    float* L = (float*)d_out;   // final f32 latents (EPIL4 writes once)
    const size_t E = E_EDGES;

    char* ws = (char*)d_ws;
    size_t off = 0;
    auto alloc = [&](size_t b) { void* p = ws + off; off += (b + 255) & ~(size_t)255; return p; };
    float*          cutb   = (float*)alloc(E * 4);
    unsigned short* wbuf   = (unsigned short*)alloc((size_t)1413120 * 2);
    float*          envb   = (float*)alloc((size_t)N_NODES * 128 * 4);
    unsigned short* scalb  = (unsigned short*)alloc(E * 64 * 2);
    unsigned short* feat2b = (unsigned short*)alloc(E * 128 * 2);
    unsigned short* Lb     = (unsigned short*)alloc(E * 512 * 2);
    int*            degcnt = (int*)alloc((size_t)2 * N_NODES * 4);
    int*            offs   = (int*)alloc((N_NODES + 1) * 4);
    int*            elist  = (int*)alloc(E * 4);
    unsigned short* A16b   = (unsigned short*)alloc(E * 32 * 2);
    unsigned short* H1b    = (unsigned short*)alloc(E * 128 * 2);
    unsigned short* H2b    = (unsigned short*)alloc(E * 256 * 2);
    unsigned short* R1b    = (unsigned short*)alloc(E * 128 * 2);
    unsigned short* NLb    = (unsigned short*)alloc(E * 512 * 2);
    unsigned short* WE1b   = (unsigned short*)alloc(E * 64 * 2);
    int* deg = degcnt;
    int* cnt = degcnt + N_NODES;

    // weight transposes+scales (one grid, 9 segments)
    unsigned short* W2b0t  = wbuf;
    unsigned short* W2b1t  = wbuf + 4096;
    unsigned short* W2b2t  = wbuf + 36864;
    unsigned short* Wenv0t = wbuf + 167936;
    unsigned short* Wlat0t = wbuf + 233472;
    unsigned short* Wlat1t = wbuf + 528384;
    unsigned short* Wenv1t = wbuf + 790528;
    unsigned short* Wfin0t = wbuf + 856064;
    unsigned short* Wfin1t = wbuf + 1150976;
    wtrans_all<<<5520, 256, 0, stream>>>(W2b0, W2b1, W2b2, Wenv0, Wlat0, Wlat1,
                                         Wenv1, Wfin0, Wfin1, wbuf);

    hipMemsetAsync(degcnt, 0, (size_t)2 * N_NODES * 4, stream);
    prep_kernel<<<E_EDGES / 256, 256, 0, stream>>>(ei, na, embed, elen, cutb, A16b, deg);
    scan_kernel<<<1, 1024, 0, stream>>>(deg, offs);
    fill_kernel<<<E_EDGES / 256, 256, 0, stream>>>(ei, offs, cnt, elist);
    sortseg_kernel<<<N_NODES / 4, 256, 0, stream>>>(offs, elist);

    // ---- two-body MLP: 16(->32) -> 128 -> 256 -> 512 (*cut) -> Lb
    gemm_bf16<1, false><<<1250, 256, 0, stream>>>(A16b, nullptr, 32, 32, W2b0t, 1, 128, 128, nullptr, H1b, nullptr, nullptr);
    gemm_bf16<1, false><<<2500, 256, 0, stream>>>(H1b, nullptr, 128, 128, W2b1t, 2, 256, 256, nullptr, H2b, nullptr, nullptr);
    gemm_bf16<2, false><<<5000, 256, 0, stream>>>(H2b, nullptr, 256, 256, W2b2t, 4, 512, 512, nullptr, Lb, cutb, nullptr);

    // ---- env-embed 0: R1b = Lb @ Wenv0t  [E,128] bf16
    gemm_bf16<0, false><<<1250, 256, 0, stream>>>(Lb, nullptr, 512, 512, Wenv0t, 1, 128, 128, nullptr, R1b, nullptr, nullptr);

    envgather_kernel<<<N_NODES / 2, 256, 0, stream>>>(R1b, 128, 64, ea, offs, elist, envb);
    tp0_kernel<<<E_EDGES / 8, 256, 0, stream>>>(R1b, ea, envb, ei, Wlin_s, Wlin_v, scalb, feat2b);

    // ---- latent resnet MLP: [Lb|scal](576) -> 512 silu -> 512, resnet into Lb
    gemm_bf16<1, true ><<<5000, 256, 0, stream>>>(Lb, scalb, 512, 576, Wlat0t, 4, 512, 512, nullptr, NLb, nullptr, nullptr);
    gemm_bf16<3, false><<<5000, 256, 0, stream>>>(NLb, nullptr, 512, 512, Wlat1t, 4, 512, 512, nullptr, Lb, cutb, rp);

    // ---- env-embed 1: WE1b = Lb @ Wenv1t  [E,64] bf16 (N padded 128)
    gemm_bf16<0, false><<<1250, 256, 0, stream>>>(Lb, nullptr, 512, 512, Wenv1t, 1, 64, 64, nullptr, WE1b, nullptr, nullptr);

    envgather_kernel<<<N_NODES / 2, 256, 0, stream>>>(WE1b, 64, 0, ea, offs, elist, envb);
    tp1_kernel<<<E_EDGES * 32 / 256, 256, 0, stream>>>(feat2b, envb, ei, scalb);

    // ---- final MLP: [Lb|scal2](576) -> 512 silu -> 512, resnet -> f32 d_out
    gemm_bf16<1, true ><<<5000, 256, 0, stream>>>(Lb, scalb, 512, 576, Wfin0t, 4, 512, 512, nullptr, NLb, nullptr, nullptr);
    gemm_bf16<4, false><<<5000, 256, 0, stream>>>(NLb, nullptr, 512, 512, Wfin1t, 4, 512, 512, L, Lb, cutb, rp);
}

// Round 5
// 1326.896 us; speedup vs baseline: 5.2722x; 1.0442x over previous
//
#include <hip/hip_runtime.h>
#include <math.h>

#define E_EDGES 160000
#define N_NODES 10000

typedef __attribute__((ext_vector_type(8))) __bf16 bf16x8;
typedef __attribute__((ext_vector_type(4))) float f32x4;
typedef __attribute__((ext_vector_type(4))) unsigned int u32x4;

__device__ __forceinline__ unsigned short f2bf(float x) {
    unsigned u = __float_as_uint(x);
    u += 0x7fff + ((u >> 16) & 1);   // round-to-nearest-even
    return (unsigned short)(u >> 16);
}
__device__ __forceinline__ float bf2f(unsigned short h) {
    return __uint_as_float(((unsigned)h) << 16);
}
__device__ __forceinline__ void gload16(const unsigned short* g, unsigned short* l) {
    __builtin_amdgcn_global_load_lds(
        (const __attribute__((address_space(1))) void*)g,
        (__attribute__((address_space(3))) void*)l, 16, 0, 0);
}

// -------------------------------------------------------------------------
// prep (+degree histogram): cutoff + 16-dim two-body rows (bf16, K pad 32)
// -------------------------------------------------------------------------
__global__ __launch_bounds__(256)
void prep_kernel(const int* __restrict__ ei, const float* __restrict__ na,
                 const float* __restrict__ embed, const float* __restrict__ elen,
                 float* __restrict__ cut, unsigned short* __restrict__ A16b,
                 int* __restrict__ deg)
{
    int e = blockIdx.x * blockDim.x + threadIdx.x;
    if (e >= E_EDGES) return;
    float r  = elen[e];
    float x  = r * (1.0f / 6.0f);
    float x2 = x * x;
    float x6 = x2 * x2 * x2;
    float c = 1.0f - 28.0f * x6 + 48.0f * x6 * x - 21.0f * x6 * x2;
    cut[e] = (x < 1.0f) ? c : 0.0f;
    int ctr = ei[e];
    int ngh = ei[E_EDGES + e];
    atomicAdd(&deg[ctr], 1);
    float4 ac = *(const float4*)(na + (size_t)ctr * 4);
    float4 an = *(const float4*)(na + (size_t)ngh * 4);
    float4 b0 = *(const float4*)(embed + (size_t)e * 8);
    float4 b1 = *(const float4*)(embed + (size_t)e * 8 + 4);
    unsigned short* o = A16b + (size_t)e * 32;
    o[0]  = f2bf(ac.x); o[1]  = f2bf(ac.y); o[2]  = f2bf(ac.z); o[3]  = f2bf(ac.w);
    o[4]  = f2bf(an.x); o[5]  = f2bf(an.y); o[6]  = f2bf(an.z); o[7]  = f2bf(an.w);
    o[8]  = f2bf(b0.x); o[9]  = f2bf(b0.y); o[10] = f2bf(b0.z); o[11] = f2bf(b0.w);
    o[12] = f2bf(b1.x); o[13] = f2bf(b1.y); o[14] = f2bf(b1.z); o[15] = f2bf(b1.w);
    #pragma unroll
    for (int i = 16; i < 32; ++i) o[i] = 0;
}

// -------------------------------------------------------------------------
// all 9 weight transposes in one grid: coalesced reads (n fastest),
// scale folded in. Bt[n*Kpad+k] = W[k*N+n] * scale.
// -------------------------------------------------------------------------
__global__ __launch_bounds__(256)
void wtrans_all(const float* __restrict__ w0, const float* __restrict__ w1,
                const float* __restrict__ w2, const float* __restrict__ w3,
                const float* __restrict__ w4, const float* __restrict__ w5,
                const float* __restrict__ w6, const float* __restrict__ w7,
                const float* __restrict__ w8, unsigned short* __restrict__ wbuf)
{
    int blk = blockIdx.x;
    const float* W; int K, N, Kpad, Npad; size_t dbase; int lstart; float sc;
    const float s16  = 0.25f;
    const float s128 = 0.088388347648318447f;
    const float s256 = 0.0625f;
    const float s512 = 0.044194173824159223f;
    const float s576 = 0.041666666666666664f;
    if      (blk <   16) { W=w0; K=16;  N=128; Kpad=32;  Npad=128; dbase=0;       lstart=0;    sc=s16;  }
    else if (blk <  144) { W=w1; K=128; N=256; Kpad=128; Npad=256; dbase=4096;    lstart=16;   sc=s128; }
    else if (blk <  656) { W=w2; K=256; N=512; Kpad=256; Npad=512; dbase=36864;   lstart=144;  sc=s256; }
    else if (blk <  912) { W=w3; K=512; N=128; Kpad=512; Npad=128; dbase=167936;  lstart=656;  sc=s512; }
    else if (blk < 2064) { W=w4; K=576; N=512; Kpad=576; Npad=512; dbase=233472;  lstart=912;  sc=s576; }
    else if (blk < 3088) { W=w5; K=512; N=512; Kpad=512; Npad=512; dbase=528384;  lstart=2064; sc=s512; }
    else if (blk < 3344) { W=w6; K=512; N=64;  Kpad=512; Npad=128; dbase=790528;  lstart=3088; sc=s512; }
    else if (blk < 4496) { W=w7; K=576; N=512; Kpad=576; Npad=512; dbase=856064;  lstart=3344; sc=s576; }
    else                 { W=w8; K=512; N=512; Kpad=512; Npad=512; dbase=1150976; lstart=4496; sc=s512; }
    int local = (blk - lstart) * 256 + threadIdx.x;
    int n = local % Npad, k = local / Npad;
    if (k >= Kpad) return;
    float v = (k < K && n < N) ? W[(size_t)k * N + n] * sc : 0.0f;
    wbuf[dbase + (size_t)n * Kpad + k] = f2bf(v);
}

// -------------------------------------------------------------------------
// CSR: scan, fill, wave-bitonic per-segment sort (deterministic)
// -------------------------------------------------------------------------
__global__ __launch_bounds__(1024)
void scan_kernel(const int* __restrict__ deg, int* __restrict__ offs)
{
    __shared__ int part[1024];
    int t = threadIdx.x;
    int base = t * 10;
    int loc[10];
    int s = 0;
    #pragma unroll
    for (int i = 0; i < 10; ++i) {
        int idx = base + i;
        int d = (idx < N_NODES) ? deg[idx] : 0;
        loc[i] = s; s += d;
    }
    part[t] = s;
    __syncthreads();
    for (int o = 1; o < 1024; o <<= 1) {
        int v = (t >= o) ? part[t - o] : 0;
        __syncthreads();
        part[t] += v;
        __syncthreads();
    }
    int excl = (t > 0) ? part[t - 1] : 0;
    #pragma unroll
    for (int i = 0; i < 10; ++i) {
        int idx = base + i;
        if (idx < N_NODES) offs[idx] = excl + loc[i];
    }
    if (t == 1023) offs[N_NODES] = part[1023];
}

__global__ __launch_bounds__(256)
void fill_kernel(const int* __restrict__ ei, const int* __restrict__ offs,
                 int* __restrict__ cnt, int* __restrict__ elist)
{
    int e = blockIdx.x * blockDim.x + threadIdx.x;
    if (e >= E_EDGES) return;
    int c = ei[e];
    int pos = offs[c] + atomicAdd(&cnt[c], 1);
    elist[pos] = e;
}

__global__ __launch_bounds__(256)
void sortseg_kernel(const int* __restrict__ offs, int* __restrict__ elist)
{
    int node = blockIdx.x * 4 + (threadIdx.x >> 6);
    int l = threadIdx.x & 63;
    if (node >= N_NODES) return;
    int b = offs[node], en = offs[node + 1];
    int deg = en - b;
    if (deg <= 1) return;
    if (deg <= 64) {
        int v = (l < deg) ? elist[b + l] : 0x7fffffff;
        #pragma unroll
        for (int k = 2; k <= 64; k <<= 1) {
            #pragma unroll
            for (int j = k >> 1; j > 0; j >>= 1) {
                int o = __shfl_xor(v, j);
                bool dirUp = ((l & k) == 0);
                bool lower = ((l & j) == 0);
                int mn = v < o ? v : o;
                int mx = v < o ? o : v;
                v = (dirUp == lower) ? mn : mx;
            }
        }
        if (l < deg) elist[b + l] = v;
    } else if (l == 0) {
        for (int i = b + 1; i < en; ++i) {
            int v = elist[i];
            int j = i - 1;
            while (j >= b && elist[j] > v) { elist[j + 1] = elist[j]; --j; }
            elist[j + 1] = v;
        }
    }
}

// -------------------------------------------------------------------------
// env gather-sum (plain stores, no memset needed)
// -------------------------------------------------------------------------
__global__ __launch_bounds__(256)
void envgather_kernel(const unsigned short* __restrict__ Wb, int wstride, int woff,
                      const float* __restrict__ ea, const int* __restrict__ offs,
                      const int* __restrict__ elist, float* __restrict__ env)
{
    int n = blockIdx.x * 2 + (threadIdx.x >> 7);
    int t = threadIdx.x & 127;
    if (n >= N_NODES) return;
    int u = t >> 2, comp = t & 3;
    int widx = woff + u * 2 + (comp ? 1 : 0);
    int beg = offs[n], end = offs[n + 1];
    float acc = 0.0f;
    for (int i = beg; i < end; ++i) {
        int e = elist[i];
        float w = bf2f(Wb[(size_t)e * wstride + widx]);
        float a = ea[(size_t)e * 4 + comp];
        acc += a * w;
    }
    env[(size_t)n * 128 + t] = acc * 0.25f;   // 1/sqrt(16)
}

// -------------------------------------------------------------------------
// bf16 MFMA GEMM, counted-vmcnt 3-deep pipeline (T3+T4 minimum recipe):
// gload_lds(16B) staging into 3 LDS buffer pairs; raw s_barrier; vmcnt(8)
// steady-state (never 0 mid-loop); setprio around MFMA cluster (T5).
// 128x128 tile, BK=32, 4 waves, XCD-bijective swizzle. Scales folded in B.
// EPIL: 0=store bf16, 1=silu->bf16, 2=*cut->bf16, 3=resnet1(bf16), 4=resnet2->f32
// -------------------------------------------------------------------------
template<int EPIL, bool CONCAT>
__global__ __launch_bounds__(256)
void gemm_bf16(const unsigned short* __restrict__ A1, const unsigned short* __restrict__ A2,
               int KA1, int K, const unsigned short* __restrict__ Bt,
               int nx, int ldc, int Nstore,
               float* __restrict__ Cf, unsigned short* __restrict__ Cb,
               const float* __restrict__ cut, const float* __restrict__ rp)
{
    // 3 double-buffers: [buf][A=0/B=1][128 rows][32 shorts]
    __shared__ __align__(16) unsigned short SB[3][2][128 * 32];
    const int tid  = threadIdx.x;
    const int lane = tid & 63;
    const int wid  = tid >> 6;
    const int wr   = wid >> 1, wc = wid & 1;
    const int nwg = gridDim.x;
    const int fid = blockIdx.x;
    const int q = nwg >> 3, r = nwg & 7;
    const int xcd = fid & 7, j = fid >> 3;
    const int L = ((xcd < r) ? xcd * (q + 1) : r * (q + 1) + (xcd - r) * q) + j;
    const int bn = (L % nx) * 128;
    const int bm = (L / nx) * 128;

    const int l15 = lane & 15;
    const int lk8 = (lane >> 4) << 3;
    const int l4r = lane >> 2;
    const int l4k = (lane & 3) << 3;
    const int KA2 = K - KA1;
    const int T   = K >> 5;    // K/32 tiles

    f32x4 acc[4][4] = {};

    // stage tile t into buffer b (4 gload_lds per thread: 2 A-chunks, 2 B-chunks)
    auto stage = [&](int t, int b) {
        int k0 = t << 5;
        #pragma unroll
        for (int i = 0; i < 2; ++i) {
            int ch  = (wid << 1) + i;          // 0..7
            int row = (ch << 4) + l4r;         // 0..127
            const unsigned short* gp;
            if (!CONCAT || k0 < KA1)
                gp = A1 + (size_t)(bm + row) * KA1 + k0 + l4k;
            else
                gp = A2 + (size_t)(bm + row) * KA2 + (k0 - KA1) + l4k;
            gload16(gp, &SB[b][0][ch << 9]);
            const unsigned short* gpb = Bt + (size_t)(bn + row) * K + k0 + l4k;
            gload16(gpb, &SB[b][1][ch << 9]);
        }
    };

    // prologue: fill up to 3 buffers
    if (T >= 1) stage(0, 0);
    if (T >= 2) stage(1, 1);
    if (T >= 3) stage(2, 2);

    for (int t = 0; t < T; ++t) {
        int rem = T - 1 - t;   // stages issued after tile t at this point
        if (rem >= 2)      asm volatile("s_waitcnt vmcnt(8)" ::: "memory");
        else if (rem == 1) asm volatile("s_waitcnt vmcnt(4)" ::: "memory");
        else               asm volatile("s_waitcnt vmcnt(0)" ::: "memory");
        __builtin_amdgcn_s_barrier();          // buf[t%3] staged by ALL waves

        const unsigned short* As = &SB[t % 3][0][0];
        const unsigned short* Bs = &SB[t % 3][1][0];
        bf16x8 af[4], bfr[4];
        #pragma unroll
        for (int m = 0; m < 4; ++m)
            af[m] = __builtin_bit_cast(bf16x8, *(const u32x4*)&As[(wr * 64 + m * 16 + l15) * 32 + lk8]);
        #pragma unroll
        for (int n = 0; n < 4; ++n)
            bfr[n] = __builtin_bit_cast(bf16x8, *(const u32x4*)&Bs[(wc * 64 + n * 16 + l15) * 32 + lk8]);
        asm volatile("s_waitcnt lgkmcnt(0)" ::: "memory");
        __builtin_amdgcn_sched_barrier(0);
        __builtin_amdgcn_s_barrier();          // all waves done reading buf[t%3]

        if (t + 3 < T) stage(t + 3, (t + 3) % 3);   // overwrite-safe prefetch

        __builtin_amdgcn_s_setprio(1);
        #pragma unroll
        for (int m = 0; m < 4; ++m)
            #pragma unroll
            for (int n = 0; n < 4; ++n)
                acc[m][n] = __builtin_amdgcn_mfma_f32_16x16x32_bf16(af[m], bfr[n], acc[m][n], 0, 0, 0);
        __builtin_amdgcn_s_setprio(0);
    }

    float c0 = 1.0f, c1 = 1.0f, c2 = 1.0f;
    if (EPIL >= 3) { c0 = __expf(rp[0]); c1 = __expf(rp[1]); c2 = __expf(rp[2]); }

    #pragma unroll
    for (int m = 0; m < 4; ++m) {
        int rbase = bm + wr * 64 + m * 16 + ((lane >> 4) << 2);
        #pragma unroll
        for (int n = 0; n < 4; ++n) {
            int col = bn + wc * 64 + n * 16 + l15;
            if (col < Nstore) {
                #pragma unroll
                for (int rr = 0; rr < 4; ++rr) {
                    int row = rbase + rr;
                    float v = acc[m][n][rr];
                    size_t off2 = (size_t)row * ldc + col;
                    if (EPIL == 0) {
                        Cb[off2] = f2bf(v);
                    } else if (EPIL == 1) {
                        v = v / (1.0f + __expf(-v));
                        Cb[off2] = f2bf(v);
                    } else if (EPIL == 2) {
                        v *= cut[row];
                        Cb[off2] = f2bf(v);
                    } else if (EPIL == 3) {
                        float old = bf2f(Cb[off2]);
                        v = (c0 * old + c1 * v * cut[row]) * rsqrtf(c0 * c0 + c1 * c1);
                        Cb[off2] = f2bf(v);
                    } else {
                        float old = bf2f(Cb[off2]);
                        float n2 = c0 * c0 + c1 * c1;
                        v = (sqrtf(n2) * old + c2 * v * cut[row]) * rsqrtf(n2 + c2 * c2);
                        Cf[off2] = v;
                    }
                }
            }
        }
    }
}

// -------------------------------------------------------------------------
// TP0 + e3nn Linear; Ws/Wv staged in LDS with alpha folded
// -------------------------------------------------------------------------
__global__ __launch_bounds__(256)
void tp0_kernel(const unsigned short* __restrict__ W0b, const float* __restrict__ ea,
                const float* __restrict__ env, const int* __restrict__ ei,
                const float* __restrict__ Ws, const float* __restrict__ Wv,
                unsigned short* __restrict__ scalb, unsigned short* __restrict__ feat2b)
{
    __shared__ float sc[8][64];
    __shared__ float xv[8][64][3];
    __shared__ float Wsl[2048];
    __shared__ float Wvl[2048];
    int tid = threadIdx.x;
    const float alpha = 0.125f;  // 1/sqrt(2U)
    #pragma unroll
    for (int i = 0; i < 8; ++i) {
        Wsl[tid + i * 256] = Ws[tid + i * 256] * alpha;
        Wvl[tid + i * 256] = Wv[tid + i * 256] * alpha;
    }
    int le = tid >> 5;
    int u  = tid & 31;
    int e  = blockIdx.x * 8 + le;
    int c  = ei[e];
    float4 a = *(const float4*)(ea + (size_t)e * 4);
    const float* ep = env + (size_t)c * 128 + u * 4;
    float e0 = ep[0], e1 = ep[1], e2 = ep[2], e3 = ep[3];
    float wf0 = bf2f(W0b[(size_t)e * 128 + u * 2]);
    float wf1 = bf2f(W0b[(size_t)e * 128 + u * 2 + 1]);
    float f0 = a.x * wf0;
    float f1 = a.y * wf1, f2 = a.z * wf1, f3 = a.w * wf1;
    const float rs3 = 0.57735026918962576f;
    float t0 = f0 * e0;
    float t1 = (f1 * e1 + f2 * e2 + f3 * e3) * rs3;
    scalb[(size_t)e * 64 + u]      = f2bf(t0);
    scalb[(size_t)e * 64 + 32 + u] = f2bf(t1);
    sc[le][u]      = t0;
    sc[le][32 + u] = t1;
    xv[le][u][0] = f0 * e1; xv[le][u][1] = f0 * e2; xv[le][u][2] = f0 * e3;
    xv[le][32 + u][0] = f1 * e0; xv[le][32 + u][1] = f2 * e0; xv[le][32 + u][2] = f3 * e0;
    __syncthreads();
    float ys = 0.0f, yv0 = 0.0f, yv1 = 0.0f, yv2 = 0.0f;
    #pragma unroll 8
    for (int k = 0; k < 64; ++k) {
        float ws = Wsl[k * 32 + u];
        float wv = Wvl[k * 32 + u];
        ys  = fmaf(sc[le][k], ws, ys);
        yv0 = fmaf(xv[le][k][0], wv, yv0);
        yv1 = fmaf(xv[le][k][1], wv, yv1);
        yv2 = fmaf(xv[le][k][2], wv, yv2);
    }
    ushort4 ov;
    ov.x = f2bf(ys);
    ov.y = f2bf(yv0);
    ov.z = f2bf(yv1);
    ov.w = f2bf(yv2);
    *(ushort4*)(feat2b + (size_t)e * 128 + u * 4) = ov;
}

// -------------------------------------------------------------------------
// TP1 (scalar outputs only) -> scalars2 bf16 [E,64]
// -------------------------------------------------------------------------
__global__ __launch_bounds__(256)
void tp1_kernel(const unsigned short* __restrict__ feat2b, const float* __restrict__ env,
                const int* __restrict__ ei, unsigned short* __restrict__ scalb)
{
    int idx = blockIdx.x * blockDim.x + threadIdx.x;
    if (idx >= E_EDGES * 32) return;
    int e = idx >> 5, u = idx & 31;
    int c = ei[e];
    const float* ep = env + (size_t)c * 128 + u * 4;
    ushort4 f4 = *(const ushort4*)(feat2b + (size_t)e * 128 + u * 4);
    float fx = bf2f(f4.x), fy = bf2f(f4.y), fz = bf2f(f4.z), fw = bf2f(f4.w);
    const float rs3 = 0.57735026918962576f;
    float t0 = fx * ep[0];
    float t1 = (fy * ep[1] + fz * ep[2] + fw * ep[3]) * rs3;
    scalb[(size_t)e * 64 + u]      = f2bf(t0);
    scalb[(size_t)e * 64 + 32 + u] = f2bf(t1);
}

// -------------------------------------------------------------------------
extern "C" void kernel_launch(void* const* d_in, const int* in_sizes, int n_in,
                              void* d_out, int out_size, void* d_ws, size_t ws_size,
                              hipStream_t stream)
{
    const int*   ei     = (const int*)d_in[0];
    const float* na     = (const float*)d_in[1];
    const float* ea     = (const float*)d_in[2];
    const float* embed  = (const float*)d_in[3];
    const float* elen   = (const float*)d_in[4];
    const float* W2b0   = (const float*)d_in[5];
    const float* W2b1   = (const float*)d_in[6];
    const float* W2b2   = (const float*)d_in[7];
    const float* Wenv0  = (const float*)d_in[8];
    const float* Wlat0  = (const float*)d_in[9];
    const float* Wlat1  = (const float*)d_in[10];
    const float* Wenv1  = (const float*)d_in[11];
    const float* Wfin0  = (const float*)d_in[12];
    const float* Wfin1  = (const float*)d_in[13];
    const float* Wlin_s = (const float*)d_in[14];
    const float* Wlin_v = (const float*)d_in[15];
    const float* rp     = (const float*)d_in[16];

    float* L = (float*)d_out;   // final f32 latents (EPIL4 writes once)
    const size_t E = E_EDGES;

    char* ws = (char*)d_ws;
    size_t off = 0;
    auto alloc = [&](size_t b) { void* p = ws + off; off += (b + 255) & ~(size_t)255; return p; };
    float*          cutb   = (float*)alloc(E * 4);
    unsigned short* wbuf   = (unsigned short*)alloc((size_t)1413120 * 2);
    float*          envb   = (float*)alloc((size_t)N_NODES * 128 * 4);
    unsigned short* scalb  = (unsigned short*)alloc(E * 64 * 2);
    unsigned short* feat2b = (unsigned short*)alloc(E * 128 * 2);
    unsigned short* Lb     = (unsigned short*)alloc(E * 512 * 2);
    int*            degcnt = (int*)alloc((size_t)2 * N_NODES * 4);
    int*            offs   = (int*)alloc((N_NODES + 1) * 4);
    int*            elist  = (int*)alloc(E * 4);
    unsigned short* A16b   = (unsigned short*)alloc(E * 32 * 2);
    unsigned short* H1b    = (unsigned short*)alloc(E * 128 * 2);
    unsigned short* H2b    = (unsigned short*)alloc(E * 256 * 2);
    unsigned short* R1b    = (unsigned short*)alloc(E * 128 * 2);
    unsigned short* NLb    = (unsigned short*)alloc(E * 512 * 2);
    unsigned short* WE1b   = (unsigned short*)alloc(E * 64 * 2);
    int* deg = degcnt;
    int* cnt = degcnt + N_NODES;

    // weight transposes+scales (one grid, 9 segments)
    unsigned short* W2b0t  = wbuf;
    unsigned short* W2b1t  = wbuf + 4096;
    unsigned short* W2b2t  = wbuf + 36864;
    unsigned short* Wenv0t = wbuf + 167936;
    unsigned short* Wlat0t = wbuf + 233472;
    unsigned short* Wlat1t = wbuf + 528384;
    unsigned short* Wenv1t = wbuf + 790528;
    unsigned short* Wfin0t = wbuf + 856064;
    unsigned short* Wfin1t = wbuf + 1150976;
    wtrans_all<<<5520, 256, 0, stream>>>(W2b0, W2b1, W2b2, Wenv0, Wlat0, Wlat1,
                                         Wenv1, Wfin0, Wfin1, wbuf);

    hipMemsetAsync(degcnt, 0, (size_t)2 * N_NODES * 4, stream);
    prep_kernel<<<E_EDGES / 256, 256, 0, stream>>>(ei, na, embed, elen, cutb, A16b, deg);
    scan_kernel<<<1, 1024, 0, stream>>>(deg, offs);
    fill_kernel<<<E_EDGES / 256, 256, 0, stream>>>(ei, offs, cnt, elist);
    sortseg_kernel<<<N_NODES / 4, 256, 0, stream>>>(offs, elist);

    // ---- two-body MLP: 16(->32) -> 128 -> 256 -> 512 (*cut) -> Lb
    gemm_bf16<1, false><<<1250, 256, 0, stream>>>(A16b, nullptr, 32, 32, W2b0t, 1, 128, 128, nullptr, H1b, nullptr, nullptr);
    gemm_bf16<1, false><<<2500, 256, 0, stream>>>(H1b, nullptr, 128, 128, W2b1t, 2, 256, 256, nullptr, H2b, nullptr, nullptr);
    gemm_bf16<2, false><<<5000, 256, 0, stream>>>(H2b, nullptr, 256, 256, W2b2t, 4, 512, 512, nullptr, Lb, cutb, nullptr);

    // ---- env-embed 0: R1b = Lb @ Wenv0t  [E,128] bf16
    gemm_bf16<0, false><<<1250, 256, 0, stream>>>(Lb, nullptr, 512, 512, Wenv0t, 1, 128, 128, nullptr, R1b, nullptr, nullptr);

    envgather_kernel<<<N_NODES / 2, 256, 0, stream>>>(R1b, 128, 64, ea, offs, elist, envb);
    tp0_kernel<<<E_EDGES / 8, 256, 0, stream>>>(R1b, ea, envb, ei, Wlin_s, Wlin_v, scalb, feat2b);

    // ---- latent resnet MLP: [Lb|scal](576) -> 512 silu -> 512, resnet into Lb
    gemm_bf16<1, true ><<<5000, 256, 0, stream>>>(Lb, scalb, 512, 576, Wlat0t, 4, 512, 512, nullptr, NLb, nullptr, nullptr);
    gemm_bf16<3, false><<<5000, 256, 0, stream>>>(NLb, nullptr, 512, 512, Wlat1t, 4, 512, 512, nullptr, Lb, cutb, rp);

    // ---- env-embed 1: WE1b = Lb @ Wenv1t  [E,64] bf16 (N padded 128)
    gemm_bf16<0, false><<<1250, 256, 0, stream>>>(Lb, nullptr, 512, 512, Wenv1t, 1, 64, 64, nullptr, WE1b, nullptr, nullptr);

    envgather_kernel<<<N_NODES / 2, 256, 0, stream>>>(WE1b, 64, 0, ea, offs, elist, envb);
    tp1_kernel<<<E_EDGES * 32 / 256, 256, 0, stream>>>(feat2b, envb, ei, scalb);

    // ---- final MLP: [Lb|scal2](576) -> 512 silu -> 512, resnet -> f32 d_out
    gemm_bf16<1, true ><<<5000, 256, 0, stream>>>(Lb, scalb, 512, 576, Wfin0t, 4, 512, 512, nullptr, NLb, nullptr, nullptr);
    gemm_bf16<4, false><<<5000, 256, 0, stream>>>(NLb, nullptr, 512, 512, Wfin1t, 4, 512, 512, L, Lb, cutb, rp);
}

// Round 6
// 1325.319 us; speedup vs baseline: 5.2785x; 1.0012x over previous
//
#include <hip/hip_runtime.h>
#include <math.h>

#define E_EDGES 160000
#define N_NODES 10000

typedef __attribute__((ext_vector_type(8))) __bf16 bf16x8;
typedef __attribute__((ext_vector_type(4))) float f32x4;
typedef __attribute__((ext_vector_type(4))) unsigned int u32x4;

__device__ __forceinline__ unsigned short f2bf(float x) {
    unsigned u = __float_as_uint(x);
    u += 0x7fff + ((u >> 16) & 1);   // round-to-nearest-even
    return (unsigned short)(u >> 16);
}
__device__ __forceinline__ float bf2f(unsigned short h) {
    return __uint_as_float(((unsigned)h) << 16);
}
__device__ __forceinline__ void gload16(const unsigned short* g, unsigned short* l) {
    __builtin_amdgcn_global_load_lds(
        (const __attribute__((address_space(1))) void*)g,
        (__attribute__((address_space(3))) void*)l, 16, 0, 0);
}

// -------------------------------------------------------------------------
// prep (+degree histogram): cutoff + 16-dim two-body rows (bf16, K pad 32)
// -------------------------------------------------------------------------
__global__ __launch_bounds__(256)
void prep_kernel(const int* __restrict__ ei, const float* __restrict__ na,
                 const float* __restrict__ embed, const float* __restrict__ elen,
                 float* __restrict__ cut, unsigned short* __restrict__ A16b,
                 int* __restrict__ deg)
{
    int e = blockIdx.x * blockDim.x + threadIdx.x;
    if (e >= E_EDGES) return;
    float r  = elen[e];
    float x  = r * (1.0f / 6.0f);
    float x2 = x * x;
    float x6 = x2 * x2 * x2;
    float c = 1.0f - 28.0f * x6 + 48.0f * x6 * x - 21.0f * x6 * x2;
    cut[e] = (x < 1.0f) ? c : 0.0f;
    int ctr = ei[e];
    int ngh = ei[E_EDGES + e];
    atomicAdd(&deg[ctr], 1);
    float4 ac = *(const float4*)(na + (size_t)ctr * 4);
    float4 an = *(const float4*)(na + (size_t)ngh * 4);
    float4 b0 = *(const float4*)(embed + (size_t)e * 8);
    float4 b1 = *(const float4*)(embed + (size_t)e * 8 + 4);
    unsigned short* o = A16b + (size_t)e * 32;
    o[0]  = f2bf(ac.x); o[1]  = f2bf(ac.y); o[2]  = f2bf(ac.z); o[3]  = f2bf(ac.w);
    o[4]  = f2bf(an.x); o[5]  = f2bf(an.y); o[6]  = f2bf(an.z); o[7]  = f2bf(an.w);
    o[8]  = f2bf(b0.x); o[9]  = f2bf(b0.y); o[10] = f2bf(b0.z); o[11] = f2bf(b0.w);
    o[12] = f2bf(b1.x); o[13] = f2bf(b1.y); o[14] = f2bf(b1.z); o[15] = f2bf(b1.w);
    #pragma unroll
    for (int i = 16; i < 32; ++i) o[i] = 0;
}

// -------------------------------------------------------------------------
// all 9 weight transposes in one grid; scale folded. Bt[n*Kpad+k]=W[k*N+n]*sc
// -------------------------------------------------------------------------
__global__ __launch_bounds__(256)
void wtrans_all(const float* __restrict__ w0, const float* __restrict__ w1,
                const float* __restrict__ w2, const float* __restrict__ w3,
                const float* __restrict__ w4, const float* __restrict__ w5,
                const float* __restrict__ w6, const float* __restrict__ w7,
                const float* __restrict__ w8, unsigned short* __restrict__ wbuf)
{
    int blk = blockIdx.x;
    const float* W; int K, N, Kpad, Npad; size_t dbase; int lstart; float sc;
    const float s16  = 0.25f;
    const float s128 = 0.088388347648318447f;
    const float s256 = 0.0625f;
    const float s512 = 0.044194173824159223f;
    const float s576 = 0.041666666666666664f;
    if      (blk <   16) { W=w0; K=16;  N=128; Kpad=32;  Npad=128; dbase=0;       lstart=0;    sc=s16;  }
    else if (blk <  144) { W=w1; K=128; N=256; Kpad=128; Npad=256; dbase=4096;    lstart=16;   sc=s128; }
    else if (blk <  656) { W=w2; K=256; N=512; Kpad=256; Npad=512; dbase=36864;   lstart=144;  sc=s256; }
    else if (blk <  912) { W=w3; K=512; N=128; Kpad=512; Npad=128; dbase=167936;  lstart=656;  sc=s512; }
    else if (blk < 2064) { W=w4; K=576; N=512; Kpad=576; Npad=512; dbase=233472;  lstart=912;  sc=s576; }
    else if (blk < 3088) { W=w5; K=512; N=512; Kpad=512; Npad=512; dbase=528384;  lstart=2064; sc=s512; }
    else if (blk < 3344) { W=w6; K=512; N=64;  Kpad=512; Npad=128; dbase=790528;  lstart=3088; sc=s512; }
    else if (blk < 4496) { W=w7; K=576; N=512; Kpad=576; Npad=512; dbase=856064;  lstart=3344; sc=s576; }
    else                 { W=w8; K=512; N=512; Kpad=512; Npad=512; dbase=1150976; lstart=4496; sc=s512; }
    int local = (blk - lstart) * 256 + threadIdx.x;
    int n = local % Npad, k = local / Npad;
    if (k >= Kpad) return;
    float v = (k < K && n < N) ? W[(size_t)k * N + n] * sc : 0.0f;
    wbuf[dbase + (size_t)n * Kpad + k] = f2bf(v);
}

// -------------------------------------------------------------------------
// CSR: scan, fill, wave-bitonic per-segment sort (deterministic)
// -------------------------------------------------------------------------
__global__ __launch_bounds__(1024)
void scan_kernel(const int* __restrict__ deg, int* __restrict__ offs)
{
    __shared__ int part[1024];
    int t = threadIdx.x;
    int base = t * 10;
    int loc[10];
    int s = 0;
    #pragma unroll
    for (int i = 0; i < 10; ++i) {
        int idx = base + i;
        int d = (idx < N_NODES) ? deg[idx] : 0;
        loc[i] = s; s += d;
    }
    part[t] = s;
    __syncthreads();
    for (int o = 1; o < 1024; o <<= 1) {
        int v = (t >= o) ? part[t - o] : 0;
        __syncthreads();
        part[t] += v;
        __syncthreads();
    }
    int excl = (t > 0) ? part[t - 1] : 0;
    #pragma unroll
    for (int i = 0; i < 10; ++i) {
        int idx = base + i;
        if (idx < N_NODES) offs[idx] = excl + loc[i];
    }
    if (t == 1023) offs[N_NODES] = part[1023];
}

__global__ __launch_bounds__(256)
void fill_kernel(const int* __restrict__ ei, const int* __restrict__ offs,
                 int* __restrict__ cnt, int* __restrict__ elist)
{
    int e = blockIdx.x * blockDim.x + threadIdx.x;
    if (e >= E_EDGES) return;
    int c = ei[e];
    int pos = offs[c] + atomicAdd(&cnt[c], 1);
    elist[pos] = e;
}

__global__ __launch_bounds__(256)
void sortseg_kernel(const int* __restrict__ offs, int* __restrict__ elist)
{
    int node = blockIdx.x * 4 + (threadIdx.x >> 6);
    int l = threadIdx.x & 63;
    if (node >= N_NODES) return;
    int b = offs[node], en = offs[node + 1];
    int deg = en - b;
    if (deg <= 1) return;
    if (deg <= 64) {
        int v = (l < deg) ? elist[b + l] : 0x7fffffff;
        #pragma unroll
        for (int k = 2; k <= 64; k <<= 1) {
            #pragma unroll
            for (int j = k >> 1; j > 0; j >>= 1) {
                int o = __shfl_xor(v, j);
                bool dirUp = ((l & k) == 0);
                bool lower = ((l & j) == 0);
                int mn = v < o ? v : o;
                int mx = v < o ? o : v;
                v = (dirUp == lower) ? mn : mx;
            }
        }
        if (l < deg) elist[b + l] = v;
    } else if (l == 0) {
        for (int i = b + 1; i < en; ++i) {
            int v = elist[i];
            int j = i - 1;
            while (j >= b && elist[j] > v) { elist[j + 1] = elist[j]; --j; }
            elist[j + 1] = v;
        }
    }
}

// -------------------------------------------------------------------------
// env gather-sum (plain stores)
// -------------------------------------------------------------------------
__global__ __launch_bounds__(256)
void envgather_kernel(const unsigned short* __restrict__ Wb, int wstride, int woff,
                      const float* __restrict__ ea, const int* __restrict__ offs,
                      const int* __restrict__ elist, float* __restrict__ env)
{
    int n = blockIdx.x * 2 + (threadIdx.x >> 7);
    int t = threadIdx.x & 127;
    if (n >= N_NODES) return;
    int u = t >> 2, comp = t & 3;
    int widx = woff + u * 2 + (comp ? 1 : 0);
    int beg = offs[n], end = offs[n + 1];
    float acc = 0.0f;
    for (int i = beg; i < end; ++i) {
        int e = elist[i];
        float w = bf2f(Wb[(size_t)e * wstride + widx]);
        float a = ea[(size_t)e * 4 + comp];
        acc += a * w;
    }
    env[(size_t)n * 128 + t] = acc * 0.25f;   // 1/sqrt(16)
}

// -------------------------------------------------------------------------
// bf16 MFMA GEMM: 128x128 tile, BK=32, 4 waves, XCD-bijective swizzle.
// 3 LDS buffer pairs, depth-2 counted-vmcnt pipeline, ONE barrier/iter.
// Bank-conflict-free via XOR slot swizzle (slot' = slot ^ ((row>>1)&3)):
// linear LDS dest + inverse-permuted global source + permuted read (rule 21).
// EPIL: 0=store bf16, 1=silu->bf16, 2=*cut->bf16, 3=resnet1(bf16), 4=resnet2->f32
// -------------------------------------------------------------------------
template<int EPIL, bool CONCAT>
__global__ __launch_bounds__(256)
void gemm_bf16(const unsigned short* __restrict__ A1, const unsigned short* __restrict__ A2,
               int KA1, int K, const unsigned short* __restrict__ Bt,
               int nx, int ldc, int Nstore,
               float* __restrict__ Cf, unsigned short* __restrict__ Cb,
               const float* __restrict__ cut, const float* __restrict__ rp)
{
    __shared__ __align__(16) unsigned short SB[3][2][128 * 32];
    const int tid  = threadIdx.x;
    const int lane = tid & 63;
    const int wid  = tid >> 6;
    const int wr   = wid >> 1, wc = wid & 1;
    const int nwg = gridDim.x;
    const int fid = blockIdx.x;
    const int q = nwg >> 3, r = nwg & 7;
    const int xcd = fid & 7, j = fid >> 3;
    const int L = ((xcd < r) ? xcd * (q + 1) : r * (q + 1) + (xcd - r) * q) + j;
    const int bn = (L % nx) * 128;
    const int bm = (L / nx) * 128;

    const int l15 = lane & 15;
    const int l4r = lane >> 2;                         // row-in-chunk 0..15
    // staging: global source 16B-slot permuted by XOR (involution)
    const int sk8 = (((lane & 3) ^ ((lane >> 3) & 3)) << 3);  // shorts
    // read: k-slot permuted by same XOR ((row>>1)&3 == (l15>>1)&3 here)
    const int rk8 = ((((lane >> 4) ^ ((l15 >> 1) & 3)) & 3) << 3);
    const int KA2 = K - KA1;
    const int T   = K >> 5;

    f32x4 acc[4][4] = {};

    auto stage = [&](int t, int b) {
        int k0 = t << 5;
        #pragma unroll
        for (int i = 0; i < 2; ++i) {
            int ch  = (wid << 1) + i;          // 0..7
            int row = (ch << 4) + l4r;         // 0..127
            const unsigned short* gp;
            if (!CONCAT || k0 < KA1)
                gp = A1 + (size_t)(bm + row) * KA1 + k0 + sk8;
            else
                gp = A2 + (size_t)(bm + row) * KA2 + (k0 - KA1) + sk8;
            gload16(gp, &SB[b][0][ch << 9]);
            const unsigned short* gpb = Bt + (size_t)(bn + row) * K + k0 + sk8;
            gload16(gpb, &SB[b][1][ch << 9]);
        }
    };

    stage(0, 0);
    if (T >= 2) stage(1, 1);

    for (int t = 0; t < T; ++t) {
        if (t < T - 1) asm volatile("s_waitcnt vmcnt(4)" ::: "memory");
        else           asm volatile("s_waitcnt vmcnt(0)" ::: "memory");
        __builtin_amdgcn_s_barrier();      // tile t staged by all; tile t-1 reads done
        __builtin_amdgcn_sched_barrier(0);

        if (t + 2 < T) stage(t + 2, (t + 2) % 3);   // overwrites buf[(t-1)%3]

        const unsigned short* As = &SB[t % 3][0][0];
        const unsigned short* Bs = &SB[t % 3][1][0];
        bf16x8 af[4], bfr[4];
        #pragma unroll
        for (int m = 0; m < 4; ++m)
            af[m] = __builtin_bit_cast(bf16x8, *(const u32x4*)&As[(wr * 64 + m * 16 + l15) * 32 + rk8]);
        #pragma unroll
        for (int n = 0; n < 4; ++n)
            bfr[n] = __builtin_bit_cast(bf16x8, *(const u32x4*)&Bs[(wc * 64 + n * 16 + l15) * 32 + rk8]);

        __builtin_amdgcn_s_setprio(1);
        #pragma unroll
        for (int m = 0; m < 4; ++m)
            #pragma unroll
            for (int n = 0; n < 4; ++n)
                acc[m][n] = __builtin_amdgcn_mfma_f32_16x16x32_bf16(af[m], bfr[n], acc[m][n], 0, 0, 0);
        __builtin_amdgcn_s_setprio(0);

        // all LDS reads of buf[t%3] retired before next barrier (rule 18)
        asm volatile("s_waitcnt lgkmcnt(0)" ::: "memory");
        __builtin_amdgcn_sched_barrier(0);
    }

    float c0 = 1.0f, c1 = 1.0f, c2 = 1.0f;
    if (EPIL >= 3) { c0 = __expf(rp[0]); c1 = __expf(rp[1]); c2 = __expf(rp[2]); }

    #pragma unroll
    for (int m = 0; m < 4; ++m) {
        int rbase = bm + wr * 64 + m * 16 + ((lane >> 4) << 2);
        #pragma unroll
        for (int n = 0; n < 4; ++n) {
            int col = bn + wc * 64 + n * 16 + l15;
            if (col < Nstore) {
                #pragma unroll
                for (int rr = 0; rr < 4; ++rr) {
                    int row = rbase + rr;
                    float v = acc[m][n][rr];
                    size_t off2 = (size_t)row * ldc + col;
                    if (EPIL == 0) {
                        Cb[off2] = f2bf(v);
                    } else if (EPIL == 1) {
                        v = v / (1.0f + __expf(-v));
                        Cb[off2] = f2bf(v);
                    } else if (EPIL == 2) {
                        v *= cut[row];
                        Cb[off2] = f2bf(v);
                    } else if (EPIL == 3) {
                        float old = bf2f(Cb[off2]);
                        v = (c0 * old + c1 * v * cut[row]) * rsqrtf(c0 * c0 + c1 * c1);
                        Cb[off2] = f2bf(v);
                    } else {
                        float old = bf2f(Cb[off2]);
                        float n2 = c0 * c0 + c1 * c1;
                        v = (sqrtf(n2) * old + c2 * v * cut[row]) * rsqrtf(n2 + c2 * c2);
                        Cf[off2] = v;
                    }
                }
            }
        }
    }
}

// -------------------------------------------------------------------------
// TP0 + e3nn Linear; Ws/Wv staged in LDS with alpha folded
// -------------------------------------------------------------------------
__global__ __launch_bounds__(256)
void tp0_kernel(const unsigned short* __restrict__ W0b, const float* __restrict__ ea,
                const float* __restrict__ env, const int* __restrict__ ei,
                const float* __restrict__ Ws, const float* __restrict__ Wv,
                unsigned short* __restrict__ scalb, unsigned short* __restrict__ feat2b)
{
    __shared__ float sc[8][64];
    __shared__ float xv[8][64][3];
    __shared__ float Wsl[2048];
    __shared__ float Wvl[2048];
    int tid = threadIdx.x;
    const float alpha = 0.125f;  // 1/sqrt(2U)
    #pragma unroll
    for (int i = 0; i < 8; ++i) {
        Wsl[tid + i * 256] = Ws[tid + i * 256] * alpha;
        Wvl[tid + i * 256] = Wv[tid + i * 256] * alpha;
    }
    int le = tid >> 5;
    int u  = tid & 31;
    int e  = blockIdx.x * 8 + le;
    int c  = ei[e];
    float4 a = *(const float4*)(ea + (size_t)e * 4);
    const float* ep = env + (size_t)c * 128 + u * 4;
    float e0 = ep[0], e1 = ep[1], e2 = ep[2], e3 = ep[3];
    float wf0 = bf2f(W0b[(size_t)e * 128 + u * 2]);
    float wf1 = bf2f(W0b[(size_t)e * 128 + u * 2 + 1]);
    float f0 = a.x * wf0;
    float f1 = a.y * wf1, f2 = a.z * wf1, f3 = a.w * wf1;
    const float rs3 = 0.57735026918962576f;
    float t0 = f0 * e0;
    float t1 = (f1 * e1 + f2 * e2 + f3 * e3) * rs3;
    scalb[(size_t)e * 64 + u]      = f2bf(t0);
    scalb[(size_t)e * 64 + 32 + u] = f2bf(t1);
    sc[le][u]      = t0;
    sc[le][32 + u] = t1;
    xv[le][u][0] = f0 * e1; xv[le][u][1] = f0 * e2; xv[le][u][2] = f0 * e3;
    xv[le][32 + u][0] = f1 * e0; xv[le][32 + u][1] = f2 * e0; xv[le][32 + u][2] = f3 * e0;
    __syncthreads();
    float ys = 0.0f, yv0 = 0.0f, yv1 = 0.0f, yv2 = 0.0f;
    #pragma unroll 8
    for (int k = 0; k < 64; ++k) {
        float ws = Wsl[k * 32 + u];
        float wv = Wvl[k * 32 + u];
        ys  = fmaf(sc[le][k], ws, ys);
        yv0 = fmaf(xv[le][k][0], wv, yv0);
        yv1 = fmaf(xv[le][k][1], wv, yv1);
        yv2 = fmaf(xv[le][k][2], wv, yv2);
    }
    ushort4 ov;
    ov.x = f2bf(ys);
    ov.y = f2bf(yv0);
    ov.z = f2bf(yv1);
    ov.w = f2bf(yv2);
    *(ushort4*)(feat2b + (size_t)e * 128 + u * 4) = ov;
}

// -------------------------------------------------------------------------
// TP1 (scalar outputs only) -> scalars2 bf16 [E,64]
// -------------------------------------------------------------------------
__global__ __launch_bounds__(256)
void tp1_kernel(const unsigned short* __restrict__ feat2b, const float* __restrict__ env,
                const int* __restrict__ ei, unsigned short* __restrict__ scalb)
{
    int idx = blockIdx.x * blockDim.x + threadIdx.x;
    if (idx >= E_EDGES * 32) return;
    int e = idx >> 5, u = idx & 31;
    int c = ei[e];
    const float* ep = env + (size_t)c * 128 + u * 4;
    ushort4 f4 = *(const ushort4*)(feat2b + (size_t)e * 128 + u * 4);
    float fx = bf2f(f4.x), fy = bf2f(f4.y), fz = bf2f(f4.z), fw = bf2f(f4.w);
    const float rs3 = 0.57735026918962576f;
    float t0 = fx * ep[0];
    float t1 = (fy * ep[1] + fz * ep[2] + fw * ep[3]) * rs3;
    scalb[(size_t)e * 64 + u]      = f2bf(t0);
    scalb[(size_t)e * 64 + 32 + u] = f2bf(t1);
}

// -------------------------------------------------------------------------
extern "C" void kernel_launch(void* const* d_in, const int* in_sizes, int n_in,
                              void* d_out, int out_size, void* d_ws, size_t ws_size,
                              hipStream_t stream)
{
    const int*   ei     = (const int*)d_in[0];
    const float* na     = (const float*)d_in[1];
    const float* ea     = (const float*)d_in[2];
    const float* embed  = (const float*)d_in[3];
    const float* elen   = (const float*)d_in[4];
    const float* W2b0   = (const float*)d_in[5];
    const float* W2b1   = (const float*)d_in[6];
    const float* W2b2   = (const float*)d_in[7];
    const float* Wenv0  = (const float*)d_in[8];
    const float* Wlat0  = (const float*)d_in[9];
    const float* Wlat1  = (const float*)d_in[10];
    const float* Wenv1  = (const float*)d_in[11];
    const float* Wfin0  = (const float*)d_in[12];
    const float* Wfin1  = (const float*)d_in[13];
    const float* Wlin_s = (const float*)d_in[14];
    const float* Wlin_v = (const float*)d_in[15];
    const float* rp     = (const float*)d_in[16];

    float* L = (float*)d_out;   // final f32 latents (EPIL4 writes once)
    const size_t E = E_EDGES;

    char* ws = (char*)d_ws;
    size_t off = 0;
    auto alloc = [&](size_t b) { void* p = ws + off; off += (b + 255) & ~(size_t)255; return p; };
    float*          cutb   = (float*)alloc(E * 4);
    unsigned short* wbuf   = (unsigned short*)alloc((size_t)1413120 * 2);
    float*          envb   = (float*)alloc((size_t)N_NODES * 128 * 4);
    unsigned short* scalb  = (unsigned short*)alloc(E * 64 * 2);
    unsigned short* feat2b = (unsigned short*)alloc(E * 128 * 2);
    unsigned short* Lb     = (unsigned short*)alloc(E * 512 * 2);
    int*            degcnt = (int*)alloc((size_t)2 * N_NODES * 4);
    int*            offs   = (int*)alloc((N_NODES + 1) * 4);
    int*            elist  = (int*)alloc(E * 4);
    unsigned short* A16b   = (unsigned short*)alloc(E * 32 * 2);
    unsigned short* H1b    = (unsigned short*)alloc(E * 128 * 2);
    unsigned short* H2b    = (unsigned short*)alloc(E * 256 * 2);
    unsigned short* R1b    = (unsigned short*)alloc(E * 128 * 2);
    unsigned short* NLb    = (unsigned short*)alloc(E * 512 * 2);
    unsigned short* WE1b   = (unsigned short*)alloc(E * 64 * 2);
    int* deg = degcnt;
    int* cnt = degcnt + N_NODES;

    unsigned short* W2b0t  = wbuf;
    unsigned short* W2b1t  = wbuf + 4096;
    unsigned short* W2b2t  = wbuf + 36864;
    unsigned short* Wenv0t = wbuf + 167936;
    unsigned short* Wlat0t = wbuf + 233472;
    unsigned short* Wlat1t = wbuf + 528384;
    unsigned short* Wenv1t = wbuf + 790528;
    unsigned short* Wfin0t = wbuf + 856064;
    unsigned short* Wfin1t = wbuf + 1150976;
    wtrans_all<<<5520, 256, 0, stream>>>(W2b0, W2b1, W2b2, Wenv0, Wlat0, Wlat1,
                                         Wenv1, Wfin0, Wfin1, wbuf);

    hipMemsetAsync(degcnt, 0, (size_t)2 * N_NODES * 4, stream);
    prep_kernel<<<E_EDGES / 256, 256, 0, stream>>>(ei, na, embed, elen, cutb, A16b, deg);
    scan_kernel<<<1, 1024, 0, stream>>>(deg, offs);
    fill_kernel<<<E_EDGES / 256, 256, 0, stream>>>(ei, offs, cnt, elist);
    sortseg_kernel<<<N_NODES / 4, 256, 0, stream>>>(offs, elist);

    // ---- two-body MLP: 16(->32) -> 128 -> 256 -> 512 (*cut) -> Lb
    gemm_bf16<1, false><<<1250, 256, 0, stream>>>(A16b, nullptr, 32, 32, W2b0t, 1, 128, 128, nullptr, H1b, nullptr, nullptr);
    gemm_bf16<1, false><<<2500, 256, 0, stream>>>(H1b, nullptr, 128, 128, W2b1t, 2, 256, 256, nullptr, H2b, nullptr, nullptr);
    gemm_bf16<2, false><<<5000, 256, 0, stream>>>(H2b, nullptr, 256, 256, W2b2t, 4, 512, 512, nullptr, Lb, cutb, nullptr);

    // ---- env-embed 0: R1b = Lb @ Wenv0t  [E,128] bf16
    gemm_bf16<0, false><<<1250, 256, 0, stream>>>(Lb, nullptr, 512, 512, Wenv0t, 1, 128, 128, nullptr, R1b, nullptr, nullptr);

    envgather_kernel<<<N_NODES / 2, 256, 0, stream>>>(R1b, 128, 64, ea, offs, elist, envb);
    tp0_kernel<<<E_EDGES / 8, 256, 0, stream>>>(R1b, ea, envb, ei, Wlin_s, Wlin_v, scalb, feat2b);

    // ---- latent resnet MLP: [Lb|scal](576) -> 512 silu -> 512, resnet into Lb
    gemm_bf16<1, true ><<<5000, 256, 0, stream>>>(Lb, scalb, 512, 576, Wlat0t, 4, 512, 512, nullptr, NLb, nullptr, nullptr);
    gemm_bf16<3, false><<<5000, 256, 0, stream>>>(NLb, nullptr, 512, 512, Wlat1t, 4, 512, 512, nullptr, Lb, cutb, rp);

    // ---- env-embed 1: WE1b = Lb @ Wenv1t  [E,64] bf16 (N padded 128)
    gemm_bf16<0, false><<<1250, 256, 0, stream>>>(Lb, nullptr, 512, 512, Wenv1t, 1, 64, 64, nullptr, WE1b, nullptr, nullptr);

    envgather_kernel<<<N_NODES / 2, 256, 0, stream>>>(WE1b, 64, 0, ea, offs, elist, envb);
    tp1_kernel<<<E_EDGES * 32 / 256, 256, 0, stream>>>(feat2b, envb, ei, scalb);

    // ---- final MLP: [Lb|scal2](576) -> 512 silu -> 512, resnet -> f32 d_out
    gemm_bf16<1, true ><<<5000, 256, 0, stream>>>(Lb, scalb, 512, 576, Wfin0t, 4, 512, 512, nullptr, NLb, nullptr, nullptr);
    gemm_bf16<4, false><<<5000, 256, 0, stream>>>(NLb, nullptr, 512, 512, Wfin1t, 4, 512, 512, L, Lb, cutb, rp);
}